// Round 15
// baseline (153.934 us; speedup 1.0000x reference)
//
#include <hip/hip_runtime.h>
#include <hip/hip_bf16.h>
#include <math.h>

typedef unsigned short u16;
typedef unsigned int u32;
typedef __attribute__((ext_vector_type(8))) short short8;
typedef __attribute__((ext_vector_type(4))) short short4v;
typedef __attribute__((ext_vector_type(4))) float f32x4;

constexpr int B  = 2;
constexpr int S  = 2048;
constexpr int D  = 1024;
constexpr int H  = 16;
constexpr int DK = 64;
constexpr int BS = B * S;   // 4096
constexpr float LOG2E = 1.4426950408889634f;

__device__ __forceinline__ u16 f2b(float f) {
    __hip_bfloat16 h = __float2bfloat16(f);
    return *reinterpret_cast<u16*>(&h);
}
__device__ __forceinline__ float b2f(short s) {
    unsigned int u = ((unsigned int)(u16)s) << 16;
    return __builtin_bit_cast(float, u);
}
__device__ __forceinline__ float fexp2(float x) { return __builtin_exp2f(x); }

#define MFMA16(a, b, c) __builtin_amdgcn_mfma_f32_16x16x32_bf16((a), (b), (c), 0, 0, 0)

// async global->LDS, 16B per lane; LDS dest is wave-uniform base + lane*16
__device__ __forceinline__ void gload16(const u16* g, u16* l) {
    __builtin_amdgcn_global_load_lds(
        (const __attribute__((address_space(1))) u32*)g,
        (__attribute__((address_space(3))) u32*)l, 16, 0, 0);
}

// ---------------------------------------------------------------------------
// fp32 -> bf16 bulk convert (8 elements/thread)
// ---------------------------------------------------------------------------
__global__ __launch_bounds__(256) void convert_x(const float* __restrict__ src,
                                                 u16* __restrict__ dst)
{
    size_t i = ((size_t)blockIdx.x * 256 + threadIdx.x) * 8;
    f32x4 a = *reinterpret_cast<const f32x4*>(src + i);
    f32x4 b = *reinterpret_cast<const f32x4*>(src + i + 4);
    short8 o;
    o[0] = (short)f2b(a[0]); o[1] = (short)f2b(a[1]);
    o[2] = (short)f2b(a[2]); o[3] = (short)f2b(a[3]);
    o[4] = (short)f2b(b[0]); o[5] = (short)f2b(b[1]);
    o[6] = (short)f2b(b[2]); o[7] = (short)f2b(b[3]);
    *reinterpret_cast<short8*>(dst + i) = o;
}

// ---------------------------------------------------------------------------
// Tiled transpose + convert: src fp32 [batch][R][C] -> dst bf16 [batch][C][R]
// ---------------------------------------------------------------------------
__global__ __launch_bounds__(256) void tconv(const float* __restrict__ src,
                                             u16* __restrict__ dst, int R, int C)
{
    const int bb = blockIdx.z;
    src += (size_t)bb * R * C;
    dst += (size_t)bb * R * C;
    const int c0 = blockIdx.x * 64, r0 = blockIdx.y * 64;
    __shared__ float Ts[64][65];
    const int tid = threadIdx.x;
    #pragma unroll
    for (int i = 0; i < 4; ++i) {
        int idx = i * 1024 + tid * 4;
        int r = idx >> 6, c = idx & 63;
        f32x4 v = *reinterpret_cast<const f32x4*>(&src[(size_t)(r0 + r) * C + c0 + c]);
        Ts[r][c] = v[0]; Ts[r][c + 1] = v[1]; Ts[r][c + 2] = v[2]; Ts[r][c + 3] = v[3];
    }
    __syncthreads();
    #pragma unroll
    for (int i = 0; i < 4; ++i) {
        int cc = i * 16 + (tid >> 4);
        int rr = (tid & 15) * 4;
        short4v pk;
        pk[0] = (short)f2b(Ts[rr][cc]);     pk[1] = (short)f2b(Ts[rr + 1][cc]);
        pk[2] = (short)f2b(Ts[rr + 2][cc]); pk[3] = (short)f2b(Ts[rr + 3][cc]);
        *reinterpret_cast<short4v*>(&dst[(size_t)(c0 + cc) * R + r0 + rr]) = pk;
    }
}

// ---------------------------------------------------------------------------
// Combined transpose+convert for the 3 QKV weights -> WT [3072][1024].
// ---------------------------------------------------------------------------
__global__ __launch_bounds__(256) void tconv3(
    const float* __restrict__ wq, const float* __restrict__ wk,
    const float* __restrict__ wv, u16* __restrict__ dst)
{
    const int z = blockIdx.z;
    const int selw = z >> 4, bb = z & 15;
    const float* src = selw == 0 ? wq : selw == 1 ? wk : wv;
    src += (size_t)bb * D * DK;
    u16* d = dst + (size_t)selw * H * DK * D + (size_t)bb * D * DK;
    const int r0 = blockIdx.y * 64;
    __shared__ float Ts[64][65];
    const int tid = threadIdx.x;
    #pragma unroll
    for (int i = 0; i < 4; ++i) {
        int idx = i * 1024 + tid * 4;
        int r = idx >> 6, c = idx & 63;
        f32x4 v = *reinterpret_cast<const f32x4*>(&src[(size_t)(r0 + r) * DK + c]);
        Ts[r][c] = v[0]; Ts[r][c + 1] = v[1]; Ts[r][c + 2] = v[2]; Ts[r][c + 3] = v[3];
    }
    __syncthreads();
    #pragma unroll
    for (int i = 0; i < 4; ++i) {
        int cc = i * 16 + (tid >> 4);
        int rr = (tid & 15) * 4;
        short4v pk;
        pk[0] = (short)f2b(Ts[rr][cc]);     pk[1] = (short)f2b(Ts[rr + 1][cc]);
        pk[2] = (short)f2b(Ts[rr + 2][cc]); pk[3] = (short)f2b(Ts[rr + 3][cc]);
        *reinterpret_cast<short4v*>(&d[(size_t)cc * D + r0 + rr]) = pk;
    }
}

// ---------------------------------------------------------------------------
// QKV projection as ONE 128x128-tile GEMM (global_load_lds staging, dbuf,
// pre-swizzled source columns).  Grid 768.  Q output pre-scaled by log2(e).
// ---------------------------------------------------------------------------
__global__ __launch_bounds__(256) void qkv_gemm(
    const u16* __restrict__ xb, const u16* __restrict__ WT,
    const float* __restrict__ bq, const float* __restrict__ bk, const float* __restrict__ bv,
    u16* __restrict__ Qw, u16* __restrict__ Kw, u16* __restrict__ Vtw)
{
    const int id   = blockIdx.x;
    const int xcd  = id & 7;
    const int j    = id >> 3;               // 0..95
    const int nblk = xcd * 3 + j % 3;       // 0..23
    const int mblk = j / 3;                 // 0..31
    const int m0 = mblk * 128, n0 = nblk * 128;
    const int sel = n0 >> 10;               // uniform per block
    const float* bias = sel == 0 ? bq : sel == 1 ? bk : bv;
    const float qscale = (sel == 0) ? LOG2E : 1.0f;

    __shared__ u16 SM[2][2][128][64];       // [buf][A/B][row][col], 64KB

    const int tid = threadIdx.x;
    const int w = tid >> 6, ln = tid & 15, hi = (tid & 63) >> 4;
    const int wm = w >> 1, wn = w & 1;
    const int l  = tid & 63;
    const int lr = l >> 3;                  // row within 8-row chunk
    const int lc8 = ((l & 7) ^ lr) * 8;     // pre-swizzled source col (u16)

    char* sA0 = (char*)&SM[0][0][0][0];
    char* sB0 = (char*)&SM[0][1][0][0];
    char* sA1 = (char*)&SM[1][0][0][0];
    char* sB1 = (char*)&SM[1][1][0][0];
    auto swz = [](int r, int cb) { return r * 128 + (cb ^ ((r & 7) << 4)); };

    f32x4 acc[4][4];
    #pragma unroll
    for (int m = 0; m < 4; ++m)
        #pragma unroll
        for (int n = 0; n < 4; ++n) acc[m][n] = f32x4{0.f, 0.f, 0.f, 0.f};

    auto stage = [&](char* sa, char* sb, int k0) {
        #pragma unroll
        for (int c = 0; c < 4; ++c) {
            int rbase = w * 32 + c * 8;         // wave-uniform chunk base
            int row = rbase + lr;
            gload16(&xb[(size_t)(m0 + row) * D + k0 + lc8], (u16*)(sa + rbase * 128));
            gload16(&WT[(size_t)(n0 + row) * D + k0 + lc8], (u16*)(sb + rbase * 128));
        }
    };

    stage(sA0, sB0, 0);
    __syncthreads();

    for (int it = 0; it < 16; ++it) {
        char* ac = (it & 1) ? sA1 : sA0;
        char* bc = (it & 1) ? sB1 : sB0;
        if (it + 1 < 16)
            stage((it & 1) ? sA0 : sA1, (it & 1) ? sB0 : sB1, (it + 1) * 64);
        #pragma unroll
        for (int ks = 0; ks < 2; ++ks) {
            short8 af[4], bf[4];
            #pragma unroll
            for (int m = 0; m < 4; ++m)
                af[m] = *reinterpret_cast<const short8*>(
                    ac + swz(wm * 64 + m * 16 + ln, ks * 64 + hi * 16));
            #pragma unroll
            for (int n = 0; n < 4; ++n)
                bf[n] = *reinterpret_cast<const short8*>(
                    bc + swz(wn * 64 + n * 16 + ln, ks * 64 + hi * 16));
            #pragma unroll
            for (int m = 0; m < 4; ++m)
                #pragma unroll
                for (int n = 0; n < 4; ++n)
                    acc[m][n] = MFMA16(af[m], bf[n], acc[m][n]);
        }
        __syncthreads();   // drains prefetch (vmcnt) + read-done for overwrite
    }

    float bias4[4];
    #pragma unroll
    for (int n = 0; n < 4; ++n)
        bias4[n] = bias[(n0 & 1023) + wn * 64 + n * 16 + ln];

    // epilogue via 32KB swizzled LDS region (SM[0])
    char* eb = sA0;
    const int bidx  = m0 >> 11;
    const int sbase = m0 & 2047;
    const int h0    = (n0 & 1023) >> 6;

    if (sel < 2) {
        #pragma unroll
        for (int m = 0; m < 4; ++m)
            #pragma unroll
            for (int n = 0; n < 4; ++n)
                #pragma unroll
                for (int r = 0; r < 4; ++r) {
                    int row = wm * 64 + m * 16 + hi * 4 + r;
                    int col = wn * 64 + n * 16 + ln;
                    *reinterpret_cast<u16*>(eb + row * 256 + ((col * 2) ^ ((row & 7) << 4))) =
                        f2b((acc[m][n][r] + bias4[n]) * qscale);
                }
        __syncthreads();
        u16* dst0 = sel == 0 ? Qw : Kw;
        #pragma unroll
        for (int c = 0; c < 8; ++c) {
            int idx = c * 256 + tid;
            int row = idx >> 4, g = idx & 15;
            short8 v = *reinterpret_cast<const short8*>(
                eb + row * 256 + ((g * 16) ^ ((row & 7) << 4)));
            int h = h0 + (g >> 3), j0 = (g & 7) * 8;
            *reinterpret_cast<short8*>(
                &dst0[((size_t)(bidx * H + h) * S + sbase + row) * DK + j0]) = v;
        }
    } else {
        #pragma unroll
        for (int m = 0; m < 4; ++m)
            #pragma unroll
            for (int n = 0; n < 4; ++n)
                #pragma unroll
                for (int r = 0; r < 4; ++r) {
                    int row = wm * 64 + m * 16 + hi * 4 + r;   // s
                    int col = wn * 64 + n * 16 + ln;           // e (2 heads)
                    *reinterpret_cast<u16*>(eb + col * 256 + ((row * 2) ^ ((col & 7) << 4))) =
                        f2b(acc[m][n][r] + bias4[n]);
                }
        __syncthreads();
        #pragma unroll
        for (int c = 0; c < 8; ++c) {
            int idx = c * 256 + tid;
            int e = idx >> 4, g = idx & 15;
            short8 v = *reinterpret_cast<const short8*>(
                eb + e * 256 + ((g * 16) ^ ((e & 7) << 4)));
            int h = h0 + (e >> 6), ein = e & 63;
            *reinterpret_cast<short8*>(
                &Vtw[((size_t)(bidx * H + h) * DK + ein) * S + sbase + g * 8]) = v;
        }
    }
}

// ---------------------------------------------------------------------------
// Column softmax denominator + fold 1/Z into V (in place).  Grid 1024,
// XCD-swizzled, descending t0.  Reg-staged Q double-buffer (round-9 form);
// exp2; diagonal tile peeled; setprio around MFMA.
// ---------------------------------------------------------------------------
__global__ __launch_bounds__(256) void col_stats(
    const u16* __restrict__ Qw, const u16* __restrict__ Kw,
    u16* __restrict__ Vtw)
{
    const int id = blockIdx.x;
    const int bh = (id & 7) * 4 + ((id >> 3) & 3);
    const int t0 = (31 - (id >> 5)) * 64;       // descending work (LPT)
    const u16* Qh = Qw + (size_t)bh * S * DK;
    const u16* Kh = Kw + (size_t)bh * S * DK;
    u16* Vh = Vtw + (size_t)bh * DK * S;

    __shared__ u16 Qs[2][64][64];
    __shared__ float zbuf[64];

    const int tid = threadIdx.x;
    const int w = tid >> 6, ln = tid & 15, hi = (tid & 63) >> 4;
    const int e0 = tid >> 3, sc = tid & 7;

    char* qb0 = (char*)&Qs[0][0][0];
    char* qb1 = (char*)&Qs[1][0][0];
    auto swz = [](int row, int colb) { return (row * 128 + colb) ^ ((row & 7) << 4); };

    short8 ak[2];
    #pragma unroll
    for (int ks = 0; ks < 2; ++ks)
        ak[ks] = *reinterpret_cast<const short8*>(
            &Kh[(size_t)(t0 + w * 16 + ln) * DK + ks * 32 + hi * 8]);

    float zs[4] = {0.f, 0.f, 0.f, 0.f};

    auto qk = [&](char* qb, f32x4 (&c)[4]) {
        #pragma unroll
        for (int n = 0; n < 4; ++n) c[n] = f32x4{0.f, 0.f, 0.f, 0.f};
        __builtin_amdgcn_s_setprio(1);
        #pragma unroll
        for (int ks = 0; ks < 2; ++ks)
            #pragma unroll
            for (int n = 0; n < 4; ++n) {
                short8 bqf = *reinterpret_cast<const short8*>(
                    qb + swz(n * 16 + ln, ks * 64 + hi * 16));
                c[n] = MFMA16(ak[ks], bqf, c[n]);
            }
        __builtin_amdgcn_s_setprio(0);
    };

    {   // stage Q rows [0,64) into qb0 (coalesced reg->LDS)
        short8 a = *reinterpret_cast<const short8*>(&Qh[(size_t)e0 * DK + sc * 8]);
        short8 b = *reinterpret_cast<const short8*>(&Qh[(size_t)(e0 + 32) * DK + sc * 8]);
        *reinterpret_cast<short8*>(qb0 + swz(e0, sc * 16)) = a;
        *reinterpret_cast<short8*>(qb0 + swz(e0 + 32, sc * 16)) = b;
    }
    __syncthreads();

    int cur = 0;
    for (int s0b = 0; s0b < t0; s0b += 64) {     // mask-free main loop
        short8 nq0 = *reinterpret_cast<const short8*>(&Qh[(size_t)(s0b + 64 + e0) * DK + sc * 8]);
        short8 nq1 = *reinterpret_cast<const short8*>(&Qh[(size_t)(s0b + 96 + e0) * DK + sc * 8]);
        f32x4 c[4];
        qk(cur ? qb1 : qb0, c);
        #pragma unroll
        for (int n = 0; n < 4; ++n)
            #pragma unroll
            for (int r = 0; r < 4; ++r)
                zs[r] += fexp2(c[n][r]);
        char* qn = cur ? qb0 : qb1;
        *reinterpret_cast<short8*>(qn + swz(e0, sc * 16)) = nq0;
        *reinterpret_cast<short8*>(qn + swz(e0 + 32, sc * 16)) = nq1;
        __syncthreads();
        cur ^= 1;
    }
    {   // peeled diagonal tile (s0b == t0), masked
        f32x4 c[4];
        qk(cur ? qb1 : qb0, c);
        #pragma unroll
        for (int n = 0; n < 4; ++n)
            #pragma unroll
            for (int r = 0; r < 4; ++r)
                zs[r] += (n * 16 + ln > w * 16 + hi * 4 + r) ? 0.f : fexp2(c[n][r]);
    }

    #pragma unroll
    for (int r = 0; r < 4; ++r) {
        #pragma unroll
        for (int msk = 1; msk < 16; msk <<= 1)
            zs[r] += __shfl_xor(zs[r], msk, 64);
    }
    if (ln == 0) {
        #pragma unroll
        for (int r = 0; r < 4; ++r)
            zbuf[w * 16 + hi * 4 + r] = 1.f / zs[r];
    }
    __syncthreads();

    float iz[8];
    #pragma unroll
    for (int j = 0; j < 8; ++j) iz[j] = zbuf[sc * 8 + j];
    #pragma unroll
    for (int pass = 0; pass < 2; ++pass) {
        int e = e0 + 32 * pass;
        u16* vp = &Vh[(size_t)e * S + t0 + sc * 8];
        short8 v = *reinterpret_cast<short8*>(vp);
        short8 o;
        #pragma unroll
        for (int j = 0; j < 8; ++j) o[j] = (short)f2b(b2f(v[j]) * iz[j]);
        *reinterpret_cast<short8*>(vp) = o;
    }
}

// ---------------------------------------------------------------------------
// P.V with V pre-scaled by 1/Z (P = exp2 of pre-scaled scores).  Grid 1024,
// XCD-swizzled.  Round-9 reg-staged V dbuf + K reg ping-pong; diagonal tile
// peeled; compile-time buffer parity; setprio; bf16 output.
// ---------------------------------------------------------------------------
__global__ __launch_bounds__(256) void attn_pv(
    const u16* __restrict__ Qw, const u16* __restrict__ Kw, const u16* __restrict__ Vtw,
    u16* __restrict__ combined)
{
    const int id = blockIdx.x;
    const int bh = (id & 7) * 4 + ((id >> 3) & 3);
    const int s0 = (id >> 5) * 64;              // s0=0 (most work) first
    const int bidx = bh >> 4, h = bh & 15;
    const u16* Qh = Qw + (size_t)bh * S * DK;
    const u16* Kh = Kw + (size_t)bh * S * DK;
    const u16* Vh = Vtw + (size_t)bh * DK * S;

    __shared__ u16 Vs[2][64][64];
    __shared__ u16 Ps[64][72];

    const int tid = threadIdx.x;
    const int w = tid >> 6, ln = tid & 15, hi = (tid & 63) >> 4;
    const int e0 = tid >> 3, sc = tid & 7;

    char* vb0 = (char*)&Vs[0][0][0];
    char* vb1 = (char*)&Vs[1][0][0];
    auto swz = [](int row, int colb) { return (row * 128 + colb) ^ ((row & 7) << 4); };

    short8 bq[4][2];
    #pragma unroll
    for (int n = 0; n < 4; ++n)
        #pragma unroll
        for (int ks = 0; ks < 2; ++ks)
            bq[n][ks] = *reinterpret_cast<const short8*>(
                &Qh[(size_t)(s0 + n * 16 + ln) * DK + ks * 32 + hi * 8]);

    f32x4 acc[4];
    #pragma unroll
    for (int n = 0; n < 4; ++n) acc[n] = f32x4{0.f, 0.f, 0.f, 0.f};

    short8 akA[2], akB[2];
    auto loadK = [&](short8 (&ak)[2], int t1) {
        #pragma unroll
        for (int ks = 0; ks < 2; ++ks)
            ak[ks] = *reinterpret_cast<const short8*>(
                &Kh[(size_t)(t1 + w * 16 + ln) * DK + ks * 32 + hi * 8]);
    };

    // one tile: load next V into regs -> QK -> exp2 -> Ps -> barrier ->
    // PV(vbc) -> write next V into vbn -> barrier.
    auto proc = [&](short8 (&ak)[2], char* vbc, char* vbn, bool diag, int t1) {
        const bool nxt = (t1 + 64 < S);
        short8 nv0, nv1;
        if (nxt) {
            nv0 = *reinterpret_cast<const short8*>(&Vh[(size_t)e0 * S + t1 + 64 + sc * 8]);
            nv1 = *reinterpret_cast<const short8*>(&Vh[(size_t)(e0 + 32) * S + t1 + 64 + sc * 8]);
        }

        f32x4 st[4];
        #pragma unroll
        for (int n = 0; n < 4; ++n) st[n] = f32x4{0.f, 0.f, 0.f, 0.f};
        __builtin_amdgcn_s_setprio(1);
        #pragma unroll
        for (int ks = 0; ks < 2; ++ks)
            #pragma unroll
            for (int n = 0; n < 4; ++n)
                st[n] = MFMA16(ak[ks], bq[n][ks], st[n]);
        __builtin_amdgcn_s_setprio(0);

        #pragma unroll
        for (int n = 0; n < 4; ++n) {
            short4v pk;
            #pragma unroll
            for (int r = 0; r < 4; ++r) {
                float pv = fexp2(st[n][r]);
                if (diag && (n * 16 + ln) > (w * 16 + hi * 4 + r)) pv = 0.f;
                pk[r] = (short)f2b(pv);
            }
            *reinterpret_cast<short4v*>(&Ps[n * 16 + ln][w * 16 + hi * 4]) = pk;
        }
        __syncthreads();   // P visible to all waves

        short8 pa[2];
        #pragma unroll
        for (int ks = 0; ks < 2; ++ks)
            pa[ks] = *reinterpret_cast<const short8*>(&Ps[w * 16 + ln][ks * 32 + hi * 8]);
        __builtin_amdgcn_s_setprio(1);
        #pragma unroll
        for (int ks = 0; ks < 2; ++ks)
            #pragma unroll
            for (int n = 0; n < 4; ++n) {
                short8 vv = *reinterpret_cast<const short8*>(
                    vbc + swz(n * 16 + ln, ks * 64 + hi * 16));
                acc[n] = MFMA16(pa[ks], vv, acc[n]);
            }
        __builtin_amdgcn_s_setprio(0);

        if (nxt) {
            *reinterpret_cast<short8*>(vbn + swz(e0, sc * 16)) = nv0;
            *reinterpret_cast<short8*>(vbn + swz(e0 + 32, sc * 16)) = nv1;
        }
        __syncthreads();   // P consumed; next V staged
    };

    {   // stage V(s0) into vb0 (coalesced reg->LDS)
        short8 a = *reinterpret_cast<const short8*>(&Vh[(size_t)e0 * S + s0 + sc * 8]);
        short8 b = *reinterpret_cast<const short8*>(&Vh[(size_t)(e0 + 32) * S + s0 + sc * 8]);
        *reinterpret_cast<short8*>(vb0 + swz(e0, sc * 16)) = a;
        *reinterpret_cast<short8*>(vb0 + swz(e0 + 32, sc * 16)) = b;
    }
    loadK(akA, s0);
    __syncthreads();

    // peeled diagonal tile (t1 = s0): vb0 / akA
    int t1 = s0;
    if (t1 + 64 < S) loadK(akB, t1 + 64);
    proc(akA, vb0, vb1, true, t1);
    t1 += 64;

    // main loop: mask-free, compile-time buffer parity
    while (t1 < S) {
        if (t1 + 64 < S) loadK(akA, t1 + 64);
        proc(akB, vb1, vb0, false, t1);
        t1 += 64;
        if (t1 >= S) break;
        if (t1 + 64 < S) loadK(akB, t1 + 64);
        proc(akA, vb0, vb1, false, t1);
        t1 += 64;
    }

    #pragma unroll
    for (int n = 0; n < 4; ++n)
        #pragma unroll
        for (int r = 0; r < 4; ++r) {
            int s = s0 + w * 16 + hi * 4 + r;
            combined[((size_t)bidx * S + s) * D + h * DK + n * 16 + ln] = f2b(acc[n][r]);
        }
}

// ---------------------------------------------------------------------------
// out = layernorm(a + bsrc(bf16)), torch semantics ((v-mean)/(std+eps),
// ddof=1).  Contiguous 4 elems/thread: f32x4 + short4v vector loads.
// ---------------------------------------------------------------------------
__global__ __launch_bounds__(256) void add_ln(
    const float* __restrict__ a, const u16* __restrict__ bsrc,
    float* __restrict__ out, u16* __restrict__ outb)
{
    const int row = blockIdx.x;
    const int tid = threadIdx.x;
    const size_t base = (size_t)row * D + tid * 4;

    f32x4 xa = *reinterpret_cast<const f32x4*>(a + base);
    float v[4];
    float sum = 0.f;
    if (bsrc) {
        short4v cb = *reinterpret_cast<const short4v*>(bsrc + base);
        #pragma unroll
        for (int i = 0; i < 4; ++i) { v[i] = xa[i] + b2f(cb[i]); sum += v[i]; }
    } else {
        #pragma unroll
        for (int i = 0; i < 4; ++i) { v[i] = xa[i]; sum += v[i]; }
    }

    __shared__ float red[8];
    #pragma unroll
    for (int o = 32; o > 0; o >>= 1) sum += __shfl_down(sum, o, 64);
    const int lane = tid & 63, w = tid >> 6;
    if (lane == 0) red[w] = sum;
    __syncthreads();
    const float mean = (red[0] + red[1] + red[2] + red[3]) * (1.f / D);

    float s2 = 0.f;
    #pragma unroll
    for (int i = 0; i < 4; ++i) { float d2 = v[i] - mean; s2 += d2 * d2; }
    #pragma unroll
    for (int o = 32; o > 0; o >>= 1) s2 += __shfl_down(s2, o, 64);
    if (lane == 0) red[4 + w] = s2;
    __syncthreads();
    const float var = (red[4] + red[5] + red[6] + red[7]) * (1.f / (D - 1));
    const float scale = 1.f / (sqrtf(var) + 1e-4f);

    f32x4 o4;
    short4v ob;
    #pragma unroll
    for (int i = 0; i < 4; ++i) {
        o4[i] = (v[i] - mean) * scale;
        ob[i] = (short)f2b(o4[i]);
    }
    *reinterpret_cast<f32x4*>(out + base) = o4;
    if (outb) *reinterpret_cast<short4v*>(outb + base) = ob;
}

// ---------------------------------------------------------------------------
// FFN: x2 = x1 + x1b @ WffT^T + bff.  1D grid 256, XCD-swizzled.
// global_load_lds + pre-swizzled-source + dbuf structure.
// ---------------------------------------------------------------------------
__global__ __launch_bounds__(256) void ffn(
    const float* __restrict__ x1, const u16* __restrict__ x1b,
    const u16* __restrict__ WffT, const float* __restrict__ bff,
    float* __restrict__ x2)
{
    const int id = blockIdx.x;
    const int m0 = ((id & 7) * 4 + ((id >> 3) & 3)) * 128;
    const int n0 = (id >> 5) * 128;

    __shared__ u16 SM[2][2][128][64];       // [buf][A/B][row][col], 64KB

    const int tid = threadIdx.x;
    const int w = tid >> 6, ln = tid & 15, hi = (tid & 63) >> 4;
    const int wm = w >> 1, wn = w & 1;
    const int l  = tid & 63;
    const int lr = l >> 3;
    const int lc8 = ((l & 7) ^ lr) * 8;

    char* sA0 = (char*)&SM[0][0][0][0];
    char* sB0 = (char*)&SM[0][1][0][0];
    char* sA1 = (char*)&SM[1][0][0][0];
    char* sB1 = (char*)&SM[1][1][0][0];
    auto swz = [](int r, int cb) { return r * 128 + (cb ^ ((r & 7) << 4)); };

    f32x4 acc[4][4];
    #pragma unroll
    for (int m = 0; m < 4; ++m)
        #pragma unroll
        for (int n = 0; n < 4; ++n) acc[m][n] = f32x4{0.f, 0.f, 0.f, 0.f};

    auto stage = [&](char* sa, char* sb, int k0) {
        #pragma unroll
        for (int c = 0; c < 4; ++c) {
            int rbase = w * 32 + c * 8;
            int row = rbase + lr;
            gload16(&x1b[(size_t)(m0 + row) * D + k0 + lc8], (u16*)(sa + rbase * 128));
            gload16(&WffT[(size_t)(n0 + row) * D + k0 + lc8], (u16*)(sb + rbase * 128));
        }
    };

    stage(sA0, sB0, 0);
    __syncthreads();

    for (int it = 0; it < 16; ++it) {
        char* ac = (it & 1) ? sA1 : sA0;
        char* bc = (it & 1) ? sB1 : sB0;
        if (it + 1 < 16)
            stage((it & 1) ? sA0 : sA1, (it & 1) ? sB0 : sB1, (it + 1) * 64);
        #pragma unroll
        for (int ks = 0; ks < 2; ++ks) {
            short8 af[4], bf[4];
            #pragma unroll
            for (int m = 0; m < 4; ++m)
                af[m] = *reinterpret_cast<const short8*>(
                    ac + swz(wm * 64 + m * 16 + ln, ks * 64 + hi * 16));
            #pragma unroll
            for (int n = 0; n < 4; ++n)
                bf[n] = *reinterpret_cast<const short8*>(
                    bc + swz(wn * 64 + n * 16 + ln, ks * 64 + hi * 16));
            #pragma unroll
            for (int m = 0; m < 4; ++m)
                #pragma unroll
                for (int n = 0; n < 4; ++n)
                    acc[m][n] = MFMA16(af[m], bf[n], acc[m][n]);
        }
        __syncthreads();
    }

    float bf4[4];
    #pragma unroll
    for (int n = 0; n < 4; ++n) bf4[n] = bff[n0 + wn * 64 + n * 16 + ln];

    #pragma unroll
    for (int m = 0; m < 4; ++m)
        #pragma unroll
        for (int n = 0; n < 4; ++n)
            #pragma unroll
            for (int r = 0; r < 4; ++r) {
                int row = m0 + wm * 64 + m * 16 + hi * 4 + r;
                int col = n0 + wn * 64 + n * 16 + ln;
                size_t idx = (size_t)row * D + col;
                x2[idx] = x1[idx] + acc[m][n][r] + bf4[n];
            }
}

// ---------------------------------------------------------------------------
extern "C" void kernel_launch(void* const* d_in, const int* in_sizes, int n_in,
                              void* d_out, int out_size, void* d_ws, size_t ws_size,
                              hipStream_t stream)
{
    const float* x   = (const float*)d_in[0];
    const float* Wq  = (const float*)d_in[1];
    const float* bq  = (const float*)d_in[2];
    const float* Wk  = (const float*)d_in[3];
    const float* bk  = (const float*)d_in[4];
    const float* Wv  = (const float*)d_in[5];
    const float* bv  = (const float*)d_in[6];
    const float* Wff = (const float*)d_in[7];
    const float* bff = (const float*)d_in[8];
    float* out = (float*)d_out;

    const size_t NX = (size_t)BS * D;          // 4,194,304
    char* p = (char*)d_ws;
    auto alloc = [&](size_t bytes) { char* r = p; p += bytes; return r; };

    u16* xb    = (u16*)alloc(NX * 2);
    u16* WT    = (u16*)alloc((size_t)3 * H * DK * D * 2);   // [3072][1024]
    u16* WffT  = (u16*)alloc((size_t)D * D * 2);
    u16* Qw    = (u16*)alloc(NX * 2);
    u16* Kw    = (u16*)alloc(NX * 2);
    u16* Vtw   = (u16*)alloc(NX * 2);
    u16* combined = (u16*)alloc(NX * 2);
    float* x1     = (float*)alloc(NX * 4);
    u16*   x1b = xb;          // xb dead after qkv_gemm
    float* x2  = (float*)Qw;  // Qw+Kw dead after attn_pv

    convert_x<<<dim3(NX / 2048), 256, 0, stream>>>(x, xb);
    tconv3<<<dim3(1, 16, 48), 256, 0, stream>>>(Wq, Wk, Wv, WT);
    tconv<<<dim3(16, 16, 1), 256, 0, stream>>>(Wff, WffT, D, D);

    qkv_gemm<<<dim3(768), 256, 0, stream>>>(
        xb, WT, bq, bk, bv, Qw, Kw, Vtw);

    col_stats<<<dim3(1024), 256, 0, stream>>>(Qw, Kw, Vtw);

    attn_pv<<<dim3(1024), 256, 0, stream>>>(Qw, Kw, Vtw, combined);

    add_ln<<<BS, 256, 0, stream>>>(x, combined, x1, x1b);

    ffn<<<dim3(256), 256, 0, stream>>>(x1, x1b, WffT, bff, x2);

    add_ln<<<BS, 256, 0, stream>>>(x2, nullptr, out, nullptr);
}

// Round 16
// 147.887 us; speedup vs baseline: 1.0409x; 1.0409x over previous
//
#include <hip/hip_runtime.h>
#include <hip/hip_bf16.h>
#include <math.h>

typedef unsigned short u16;
typedef unsigned int u32;
typedef __attribute__((ext_vector_type(8))) short short8;
typedef __attribute__((ext_vector_type(4))) short short4v;
typedef __attribute__((ext_vector_type(4))) float f32x4;

constexpr int B  = 2;
constexpr int S  = 2048;
constexpr int D  = 1024;
constexpr int H  = 16;
constexpr int DK = 64;
constexpr int BS = B * S;   // 4096

__device__ __forceinline__ u16 f2b(float f) {
    __hip_bfloat16 h = __float2bfloat16(f);
    return *reinterpret_cast<u16*>(&h);
}
__device__ __forceinline__ float b2f(short s) {
    unsigned int u = ((unsigned int)(u16)s) << 16;
    return __builtin_bit_cast(float, u);
}

#define MFMA16(a, b, c) __builtin_amdgcn_mfma_f32_16x16x32_bf16((a), (b), (c), 0, 0, 0)

// async global->LDS, 16B per lane; LDS dest is wave-uniform base + lane*16
__device__ __forceinline__ void gload16(const u16* g, u16* l) {
    __builtin_amdgcn_global_load_lds(
        (const __attribute__((address_space(1))) u32*)g,
        (__attribute__((address_space(3))) u32*)l, 16, 0, 0);
}

// ---------------------------------------------------------------------------
// fp32 -> bf16 bulk convert (8 elements/thread)
// ---------------------------------------------------------------------------
__global__ __launch_bounds__(256) void convert_x(const float* __restrict__ src,
                                                 u16* __restrict__ dst)
{
    size_t i = ((size_t)blockIdx.x * 256 + threadIdx.x) * 8;
    f32x4 a = *reinterpret_cast<const f32x4*>(src + i);
    f32x4 b = *reinterpret_cast<const f32x4*>(src + i + 4);
    short8 o;
    o[0] = (short)f2b(a[0]); o[1] = (short)f2b(a[1]);
    o[2] = (short)f2b(a[2]); o[3] = (short)f2b(a[3]);
    o[4] = (short)f2b(b[0]); o[5] = (short)f2b(b[1]);
    o[6] = (short)f2b(b[2]); o[7] = (short)f2b(b[3]);
    *reinterpret_cast<short8*>(dst + i) = o;
}

// ---------------------------------------------------------------------------
// Tiled transpose + convert: src fp32 [batch][R][C] -> dst bf16 [batch][C][R]
// ---------------------------------------------------------------------------
__global__ __launch_bounds__(256) void tconv(const float* __restrict__ src,
                                             u16* __restrict__ dst, int R, int C)
{
    const int bb = blockIdx.z;
    src += (size_t)bb * R * C;
    dst += (size_t)bb * R * C;
    const int c0 = blockIdx.x * 64, r0 = blockIdx.y * 64;
    __shared__ float Ts[64][65];
    const int tid = threadIdx.x;
    #pragma unroll
    for (int i = 0; i < 4; ++i) {
        int idx = i * 1024 + tid * 4;
        int r = idx >> 6, c = idx & 63;
        f32x4 v = *reinterpret_cast<const f32x4*>(&src[(size_t)(r0 + r) * C + c0 + c]);
        Ts[r][c] = v[0]; Ts[r][c + 1] = v[1]; Ts[r][c + 2] = v[2]; Ts[r][c + 3] = v[3];
    }
    __syncthreads();
    #pragma unroll
    for (int i = 0; i < 4; ++i) {
        int cc = i * 16 + (tid >> 4);
        int rr = (tid & 15) * 4;
        short4v pk;
        pk[0] = (short)f2b(Ts[rr][cc]);     pk[1] = (short)f2b(Ts[rr + 1][cc]);
        pk[2] = (short)f2b(Ts[rr + 2][cc]); pk[3] = (short)f2b(Ts[rr + 3][cc]);
        *reinterpret_cast<short4v*>(&dst[(size_t)(c0 + cc) * R + r0 + rr]) = pk;
    }
}

// ---------------------------------------------------------------------------
// Combined transpose+convert for the 3 QKV weights -> WT [3072][1024].
// grid (1, 16, 48): z/16 selects Wq/Wk/Wv, z%16 is the head.
// ---------------------------------------------------------------------------
__global__ __launch_bounds__(256) void tconv3(
    const float* __restrict__ wq, const float* __restrict__ wk,
    const float* __restrict__ wv, u16* __restrict__ dst)
{
    const int z = blockIdx.z;
    const int selw = z >> 4, bb = z & 15;
    const float* src = selw == 0 ? wq : selw == 1 ? wk : wv;
    src += (size_t)bb * D * DK;
    u16* d = dst + (size_t)selw * H * DK * D + (size_t)bb * D * DK;
    const int r0 = blockIdx.y * 64;
    __shared__ float Ts[64][65];
    const int tid = threadIdx.x;
    #pragma unroll
    for (int i = 0; i < 4; ++i) {
        int idx = i * 1024 + tid * 4;
        int r = idx >> 6, c = idx & 63;
        f32x4 v = *reinterpret_cast<const f32x4*>(&src[(size_t)(r0 + r) * DK + c]);
        Ts[r][c] = v[0]; Ts[r][c + 1] = v[1]; Ts[r][c + 2] = v[2]; Ts[r][c + 3] = v[3];
    }
    __syncthreads();
    #pragma unroll
    for (int i = 0; i < 4; ++i) {
        int cc = i * 16 + (tid >> 4);
        int rr = (tid & 15) * 4;
        short4v pk;
        pk[0] = (short)f2b(Ts[rr][cc]);     pk[1] = (short)f2b(Ts[rr + 1][cc]);
        pk[2] = (short)f2b(Ts[rr + 2][cc]); pk[3] = (short)f2b(Ts[rr + 3][cc]);
        *reinterpret_cast<short4v*>(&d[(size_t)cc * D + r0 + rr]) = pk;
    }
}

// ---------------------------------------------------------------------------
// QKV projection as ONE 128x128-tile GEMM (global_load_lds staging, dbuf,
// pre-swizzled source columns).  Grid 768.
// ---------------------------------------------------------------------------
__global__ __launch_bounds__(256) void qkv_gemm(
    const u16* __restrict__ xb, const u16* __restrict__ WT,
    const float* __restrict__ bq, const float* __restrict__ bk, const float* __restrict__ bv,
    u16* __restrict__ Qw, u16* __restrict__ Kw, u16* __restrict__ Vtw)
{
    const int id   = blockIdx.x;
    const int xcd  = id & 7;
    const int j    = id >> 3;               // 0..95
    const int nblk = xcd * 3 + j % 3;       // 0..23
    const int mblk = j / 3;                 // 0..31
    const int m0 = mblk * 128, n0 = nblk * 128;
    const int sel = n0 >> 10;               // uniform per block
    const float* bias = sel == 0 ? bq : sel == 1 ? bk : bv;

    __shared__ u16 SM[2][2][128][64];       // [buf][A/B][row][col], 64KB

    const int tid = threadIdx.x;
    const int w = tid >> 6, ln = tid & 15, hi = (tid & 63) >> 4;
    const int wm = w >> 1, wn = w & 1;
    const int l  = tid & 63;
    const int lr = l >> 3;                  // row within 8-row chunk
    const int lc8 = ((l & 7) ^ lr) * 8;     // pre-swizzled source col (u16)

    char* sA0 = (char*)&SM[0][0][0][0];
    char* sB0 = (char*)&SM[0][1][0][0];
    char* sA1 = (char*)&SM[1][0][0][0];
    char* sB1 = (char*)&SM[1][1][0][0];
    auto swz = [](int r, int cb) { return r * 128 + (cb ^ ((r & 7) << 4)); };

    f32x4 acc[4][4];
    #pragma unroll
    for (int m = 0; m < 4; ++m)
        #pragma unroll
        for (int n = 0; n < 4; ++n) acc[m][n] = f32x4{0.f, 0.f, 0.f, 0.f};

    auto stage = [&](char* sa, char* sb, int k0) {
        #pragma unroll
        for (int c = 0; c < 4; ++c) {
            int rbase = w * 32 + c * 8;         // wave-uniform chunk base
            int row = rbase + lr;
            gload16(&xb[(size_t)(m0 + row) * D + k0 + lc8], (u16*)(sa + rbase * 128));
            gload16(&WT[(size_t)(n0 + row) * D + k0 + lc8], (u16*)(sb + rbase * 128));
        }
    };

    stage(sA0, sB0, 0);
    __syncthreads();

    for (int it = 0; it < 16; ++it) {
        char* ac = (it & 1) ? sA1 : sA0;
        char* bc = (it & 1) ? sB1 : sB0;
        if (it + 1 < 16)
            stage((it & 1) ? sA0 : sA1, (it & 1) ? sB0 : sB1, (it + 1) * 64);
        #pragma unroll
        for (int ks = 0; ks < 2; ++ks) {
            short8 af[4], bf[4];
            #pragma unroll
            for (int m = 0; m < 4; ++m)
                af[m] = *reinterpret_cast<const short8*>(
                    ac + swz(wm * 64 + m * 16 + ln, ks * 64 + hi * 16));
            #pragma unroll
            for (int n = 0; n < 4; ++n)
                bf[n] = *reinterpret_cast<const short8*>(
                    bc + swz(wn * 64 + n * 16 + ln, ks * 64 + hi * 16));
            #pragma unroll
            for (int m = 0; m < 4; ++m)
                #pragma unroll
                for (int n = 0; n < 4; ++n)
                    acc[m][n] = MFMA16(af[m], bf[n], acc[m][n]);
        }
        __syncthreads();   // drains prefetch (vmcnt) + read-done for overwrite
    }

    float bias4[4];
    #pragma unroll
    for (int n = 0; n < 4; ++n)
        bias4[n] = bias[(n0 & 1023) + wn * 64 + n * 16 + ln];

    // epilogue via 32KB swizzled LDS region (SM[0])
    char* eb = sA0;
    const int bidx  = m0 >> 11;
    const int sbase = m0 & 2047;
    const int h0    = (n0 & 1023) >> 6;

    if (sel < 2) {
        #pragma unroll
        for (int m = 0; m < 4; ++m)
            #pragma unroll
            for (int n = 0; n < 4; ++n)
                #pragma unroll
                for (int r = 0; r < 4; ++r) {
                    int row = wm * 64 + m * 16 + hi * 4 + r;
                    int col = wn * 64 + n * 16 + ln;
                    *reinterpret_cast<u16*>(eb + row * 256 + ((col * 2) ^ ((row & 7) << 4))) =
                        f2b(acc[m][n][r] + bias4[n]);
                }
        __syncthreads();
        u16* dst0 = sel == 0 ? Qw : Kw;
        #pragma unroll
        for (int c = 0; c < 8; ++c) {
            int idx = c * 256 + tid;
            int row = idx >> 4, g = idx & 15;
            short8 v = *reinterpret_cast<const short8*>(
                eb + row * 256 + ((g * 16) ^ ((row & 7) << 4)));
            int h = h0 + (g >> 3), j0 = (g & 7) * 8;
            *reinterpret_cast<short8*>(
                &dst0[((size_t)(bidx * H + h) * S + sbase + row) * DK + j0]) = v;
        }
    } else {
        #pragma unroll
        for (int m = 0; m < 4; ++m)
            #pragma unroll
            for (int n = 0; n < 4; ++n)
                #pragma unroll
                for (int r = 0; r < 4; ++r) {
                    int row = wm * 64 + m * 16 + hi * 4 + r;   // s
                    int col = wn * 64 + n * 16 + ln;           // e (2 heads)
                    *reinterpret_cast<u16*>(eb + col * 256 + ((row * 2) ^ ((col & 7) << 4))) =
                        f2b(acc[m][n][r] + bias4[n]);
                }
        __syncthreads();
        #pragma unroll
        for (int c = 0; c < 8; ++c) {
            int idx = c * 256 + tid;
            int e = idx >> 4, g = idx & 15;
            short8 v = *reinterpret_cast<const short8*>(
                eb + e * 256 + ((g * 16) ^ ((e & 7) << 4)));
            int h = h0 + (e >> 6), ein = e & 63;
            *reinterpret_cast<short8*>(
                &Vtw[((size_t)(bidx * H + h) * DK + ein) * S + sbase + g * 8]) = v;
        }
    }
}

// ---------------------------------------------------------------------------
// Column softmax denominator + fold 1/Z into V (in place).  Round-9 form:
// grid 1024, XCD-swizzled, descending t0 (heaviest first).
// ---------------------------------------------------------------------------
__global__ __launch_bounds__(256) void col_stats(
    const u16* __restrict__ Qw, const u16* __restrict__ Kw,
    u16* __restrict__ Vtw)
{
    const int id = blockIdx.x;
    const int bh = (id & 7) * 4 + ((id >> 3) & 3);
    const int t0 = (31 - (id >> 5)) * 64;       // descending work (LPT)
    const u16* Qh = Qw + (size_t)bh * S * DK;
    const u16* Kh = Kw + (size_t)bh * S * DK;
    u16* Vh = Vtw + (size_t)bh * DK * S;

    __shared__ u16 Qs[2][64][64];
    __shared__ float zbuf[64];

    const int tid = threadIdx.x;
    const int w = tid >> 6, ln = tid & 15, hi = (tid & 63) >> 4;
    const int e0 = tid >> 3, sc = tid & 7;

    char* qb0 = (char*)&Qs[0][0][0];
    char* qb1 = (char*)&Qs[1][0][0];
    auto swz = [](int row, int colb) { return (row * 128 + colb) ^ ((row & 7) << 4); };

    short8 ak[2];
    #pragma unroll
    for (int ks = 0; ks < 2; ++ks)
        ak[ks] = *reinterpret_cast<const short8*>(
            &Kh[(size_t)(t0 + w * 16 + ln) * DK + ks * 32 + hi * 8]);

    float zs[4] = {0.f, 0.f, 0.f, 0.f};

    {
        short8 a = *reinterpret_cast<const short8*>(&Qh[(size_t)e0 * DK + sc * 8]);
        short8 b = *reinterpret_cast<const short8*>(&Qh[(size_t)(e0 + 32) * DK + sc * 8]);
        *reinterpret_cast<short8*>(qb0 + swz(e0, sc * 16)) = a;
        *reinterpret_cast<short8*>(qb0 + swz(e0 + 32, sc * 16)) = b;
    }
    __syncthreads();

    int cur = 0;
    for (int s0b = 0; s0b <= t0; s0b += 64) {
        const bool nxt = (s0b + 64 <= t0);
        short8 nq0, nq1;
        if (nxt) {
            nq0 = *reinterpret_cast<const short8*>(&Qh[(size_t)(s0b + 64 + e0) * DK + sc * 8]);
            nq1 = *reinterpret_cast<const short8*>(&Qh[(size_t)(s0b + 96 + e0) * DK + sc * 8]);
        }
        char* qb = cur ? qb1 : qb0;
        f32x4 c[4];
        #pragma unroll
        for (int n = 0; n < 4; ++n) c[n] = f32x4{0.f, 0.f, 0.f, 0.f};
        #pragma unroll
        for (int ks = 0; ks < 2; ++ks)
            #pragma unroll
            for (int n = 0; n < 4; ++n) {
                short8 bqf = *reinterpret_cast<const short8*>(
                    qb + swz(n * 16 + ln, ks * 64 + hi * 16));
                c[n] = MFMA16(ak[ks], bqf, c[n]);
            }
        if (s0b == t0) {
            #pragma unroll
            for (int n = 0; n < 4; ++n)
                #pragma unroll
                for (int r = 0; r < 4; ++r)
                    if (s0b + n * 16 + ln > t0 + w * 16 + hi * 4 + r)
                        c[n][r] = -INFINITY;
        }
        #pragma unroll
        for (int n = 0; n < 4; ++n)
            #pragma unroll
            for (int r = 0; r < 4; ++r)
                zs[r] += __expf(c[n][r]);
        if (nxt) {
            char* qn = cur ? qb0 : qb1;
            *reinterpret_cast<short8*>(qn + swz(e0, sc * 16)) = nq0;
            *reinterpret_cast<short8*>(qn + swz(e0 + 32, sc * 16)) = nq1;
        }
        __syncthreads();
        cur ^= 1;
    }

    #pragma unroll
    for (int r = 0; r < 4; ++r) {
        #pragma unroll
        for (int msk = 1; msk < 16; msk <<= 1)
            zs[r] += __shfl_xor(zs[r], msk, 64);
    }
    if (ln == 0) {
        #pragma unroll
        for (int r = 0; r < 4; ++r)
            zbuf[w * 16 + hi * 4 + r] = 1.f / zs[r];
    }
    __syncthreads();

    float iz[8];
    #pragma unroll
    for (int j = 0; j < 8; ++j) iz[j] = zbuf[sc * 8 + j];
    #pragma unroll
    for (int pass = 0; pass < 2; ++pass) {
        int e = e0 + 32 * pass;
        u16* vp = &Vh[(size_t)e * S + t0 + sc * 8];
        short8 v = *reinterpret_cast<short8*>(vp);
        short8 o;
        #pragma unroll
        for (int j = 0; j < 8; ++j) o[j] = (short)f2b(b2f(v[j]) * iz[j]);
        *reinterpret_cast<short8*>(vp) = o;
    }
}

// ---------------------------------------------------------------------------
// P.V with V pre-scaled by 1/Z (P = raw exp).  Round-9 form: grid 1024,
// XCD-swizzled; V reg-staged into LDS dbuf; K reg ping-pong; 2 barriers/tile.
// ---------------------------------------------------------------------------
__global__ __launch_bounds__(256) void attn_pv(
    const u16* __restrict__ Qw, const u16* __restrict__ Kw, const u16* __restrict__ Vtw,
    float* __restrict__ combined)
{
    const int id = blockIdx.x;
    const int bh = (id & 7) * 4 + ((id >> 3) & 3);
    const int s0 = (id >> 5) * 64;              // s0=0 (most work) first
    const int bidx = bh >> 4, h = bh & 15;
    const u16* Qh = Qw + (size_t)bh * S * DK;
    const u16* Kh = Kw + (size_t)bh * S * DK;
    const u16* Vh = Vtw + (size_t)bh * DK * S;

    __shared__ u16 Vs[2][64][64];
    __shared__ u16 Ps[64][72];

    const int tid = threadIdx.x;
    const int w = tid >> 6, ln = tid & 15, hi = (tid & 63) >> 4;
    const int e0 = tid >> 3, sc = tid & 7;

    char* vb0 = (char*)&Vs[0][0][0];
    char* vb1 = (char*)&Vs[1][0][0];
    auto swz = [](int row, int colb) { return (row * 128 + colb) ^ ((row & 7) << 4); };

    short8 bq[4][2];
    #pragma unroll
    for (int n = 0; n < 4; ++n)
        #pragma unroll
        for (int ks = 0; ks < 2; ++ks)
            bq[n][ks] = *reinterpret_cast<const short8*>(
                &Qh[(size_t)(s0 + n * 16 + ln) * DK + ks * 32 + hi * 8]);

    f32x4 acc[4];
    #pragma unroll
    for (int n = 0; n < 4; ++n) acc[n] = f32x4{0.f, 0.f, 0.f, 0.f};

    {
        short8 a = *reinterpret_cast<const short8*>(&Vh[(size_t)e0 * S + s0 + sc * 8]);
        short8 b = *reinterpret_cast<const short8*>(&Vh[(size_t)(e0 + 32) * S + s0 + sc * 8]);
        *reinterpret_cast<short8*>(vb0 + swz(e0, sc * 16)) = a;
        *reinterpret_cast<short8*>(vb0 + swz(e0 + 32, sc * 16)) = b;
    }

    short8 akA[2], akB[2];
    auto loadK = [&](short8 (&ak)[2], int t1) {
        #pragma unroll
        for (int ks = 0; ks < 2; ++ks)
            ak[ks] = *reinterpret_cast<const short8*>(
                &Kh[(size_t)(t1 + w * 16 + ln) * DK + ks * 32 + hi * 8]);
    };

    loadK(akA, s0);
    __syncthreads();
    int cur = 0;

    auto tile = [&](short8 (&ak)[2], int t1) {
        const bool nxt = (t1 + 64 < S);
        short8 nv0, nv1;
        if (nxt) {
            nv0 = *reinterpret_cast<const short8*>(&Vh[(size_t)e0 * S + t1 + 64 + sc * 8]);
            nv1 = *reinterpret_cast<const short8*>(&Vh[(size_t)(e0 + 32) * S + t1 + 64 + sc * 8]);
        }

        f32x4 st[4];
        #pragma unroll
        for (int n = 0; n < 4; ++n) st[n] = f32x4{0.f, 0.f, 0.f, 0.f};
        #pragma unroll
        for (int ks = 0; ks < 2; ++ks)
            #pragma unroll
            for (int n = 0; n < 4; ++n)
                st[n] = MFMA16(ak[ks], bq[n][ks], st[n]);

        const bool diag = (t1 == s0);
        #pragma unroll
        for (int n = 0; n < 4; ++n) {
            short4v pk;
            #pragma unroll
            for (int r = 0; r < 4; ++r) {
                float p = __expf(st[n][r]);
                if (diag && (s0 + n * 16 + ln) > (t1 + w * 16 + hi * 4 + r)) p = 0.f;
                pk[r] = (short)f2b(p);
            }
            *reinterpret_cast<short4v*>(&Ps[n * 16 + ln][w * 16 + hi * 4]) = pk;
        }
        __syncthreads();   // P visible to all waves

        char* vb = cur ? vb1 : vb0;
        short8 pa[2];
        #pragma unroll
        for (int ks = 0; ks < 2; ++ks)
            pa[ks] = *reinterpret_cast<const short8*>(&Ps[w * 16 + ln][ks * 32 + hi * 8]);
        #pragma unroll
        for (int ks = 0; ks < 2; ++ks)
            #pragma unroll
            for (int n = 0; n < 4; ++n) {
                short8 vv = *reinterpret_cast<const short8*>(
                    vb + swz(n * 16 + ln, ks * 64 + hi * 16));
                acc[n] = MFMA16(pa[ks], vv, acc[n]);
            }

        if (nxt) {
            char* vn = cur ? vb0 : vb1;
            *reinterpret_cast<short8*>(vn + swz(e0, sc * 16)) = nv0;
            *reinterpret_cast<short8*>(vn + swz(e0 + 32, sc * 16)) = nv1;
        }
        __syncthreads();   // P consumed; next V staged
        cur ^= 1;
    };

    int t1 = s0;
    while (t1 < S) {
        if (t1 + 64 < S) loadK(akB, t1 + 64);
        tile(akA, t1);
        t1 += 64;
        if (t1 >= S) break;
        if (t1 + 64 < S) loadK(akA, t1 + 64);
        tile(akB, t1);
        t1 += 64;
    }

    #pragma unroll
    for (int n = 0; n < 4; ++n)
        #pragma unroll
        for (int r = 0; r < 4; ++r) {
            int s = s0 + w * 16 + hi * 4 + r;
            combined[((size_t)bidx * S + s) * D + h * DK + n * 16 + ln] = acc[n][r];
        }
}

// ---------------------------------------------------------------------------
// out = layernorm(a + bsrc), torch semantics ((v-mean)/(std+eps), ddof=1).
// ---------------------------------------------------------------------------
__global__ __launch_bounds__(256) void add_ln(
    const float* __restrict__ a, const float* __restrict__ bsrc,
    float* __restrict__ out, u16* __restrict__ outb)
{
    const int row = blockIdx.x;
    const int tid = threadIdx.x;
    const size_t base = (size_t)row * D;

    float v[4];
    float sum = 0.f;
    #pragma unroll
    for (int i = 0; i < 4; ++i) {
        int c = tid + i * 256;
        float t = a[base + c];
        if (bsrc) t += bsrc[base + c];
        v[i] = t;
        sum += t;
    }

    __shared__ float red[8];
    #pragma unroll
    for (int o = 32; o > 0; o >>= 1) sum += __shfl_down(sum, o, 64);
    const int lane = tid & 63, w = tid >> 6;
    if (lane == 0) red[w] = sum;
    __syncthreads();
    const float mean = (red[0] + red[1] + red[2] + red[3]) * (1.f / D);

    float s2 = 0.f;
    #pragma unroll
    for (int i = 0; i < 4; ++i) { float d2 = v[i] - mean; s2 += d2 * d2; }
    #pragma unroll
    for (int o = 32; o > 0; o >>= 1) s2 += __shfl_down(s2, o, 64);
    if (lane == 0) red[4 + w] = s2;
    __syncthreads();
    const float var = (red[4] + red[5] + red[6] + red[7]) * (1.f / (D - 1));
    const float scale = 1.f / (sqrtf(var) + 1e-4f);

    #pragma unroll
    for (int i = 0; i < 4; ++i) {
        int c = tid + i * 256;
        float o = (v[i] - mean) * scale;
        out[base + c] = o;
        if (outb) outb[base + c] = f2b(o);
    }
}

// ---------------------------------------------------------------------------
// FFN: x2 = x1 + x1b @ WffT^T + bff.  1D grid 256, XCD-swizzled.
// global_load_lds + pre-swizzled-source + dbuf structure.
// ---------------------------------------------------------------------------
__global__ __launch_bounds__(256) void ffn(
    const float* __restrict__ x1, const u16* __restrict__ x1b,
    const u16* __restrict__ WffT, const float* __restrict__ bff,
    float* __restrict__ x2)
{
    const int id = blockIdx.x;
    const int m0 = ((id & 7) * 4 + ((id >> 3) & 3)) * 128;
    const int n0 = (id >> 5) * 128;

    __shared__ u16 SM[2][2][128][64];       // [buf][A/B][row][col], 64KB

    const int tid = threadIdx.x;
    const int w = tid >> 6, ln = tid & 15, hi = (tid & 63) >> 4;
    const int wm = w >> 1, wn = w & 1;
    const int l  = tid & 63;
    const int lr = l >> 3;
    const int lc8 = ((l & 7) ^ lr) * 8;

    char* sA0 = (char*)&SM[0][0][0][0];
    char* sB0 = (char*)&SM[0][1][0][0];
    char* sA1 = (char*)&SM[1][0][0][0];
    char* sB1 = (char*)&SM[1][1][0][0];
    auto swz = [](int r, int cb) { return r * 128 + (cb ^ ((r & 7) << 4)); };

    f32x4 acc[4][4];
    #pragma unroll
    for (int m = 0; m < 4; ++m)
        #pragma unroll
        for (int n = 0; n < 4; ++n) acc[m][n] = f32x4{0.f, 0.f, 0.f, 0.f};

    auto stage = [&](char* sa, char* sb, int k0) {
        #pragma unroll
        for (int c = 0; c < 4; ++c) {
            int rbase = w * 32 + c * 8;
            int row = rbase + lr;
            gload16(&x1b[(size_t)(m0 + row) * D + k0 + lc8], (u16*)(sa + rbase * 128));
            gload16(&WffT[(size_t)(n0 + row) * D + k0 + lc8], (u16*)(sb + rbase * 128));
        }
    };

    stage(sA0, sB0, 0);
    __syncthreads();

    for (int it = 0; it < 16; ++it) {
        char* ac = (it & 1) ? sA1 : sA0;
        char* bc = (it & 1) ? sB1 : sB0;
        if (it + 1 < 16)
            stage((it & 1) ? sA0 : sA1, (it & 1) ? sB0 : sB1, (it + 1) * 64);
        #pragma unroll
        for (int ks = 0; ks < 2; ++ks) {
            short8 af[4], bf[4];
            #pragma unroll
            for (int m = 0; m < 4; ++m)
                af[m] = *reinterpret_cast<const short8*>(
                    ac + swz(wm * 64 + m * 16 + ln, ks * 64 + hi * 16));
            #pragma unroll
            for (int n = 0; n < 4; ++n)
                bf[n] = *reinterpret_cast<const short8*>(
                    bc + swz(wn * 64 + n * 16 + ln, ks * 64 + hi * 16));
            #pragma unroll
            for (int m = 0; m < 4; ++m)
                #pragma unroll
                for (int n = 0; n < 4; ++n)
                    acc[m][n] = MFMA16(af[m], bf[n], acc[m][n]);
        }
        __syncthreads();
    }

    float bf4[4];
    #pragma unroll
    for (int n = 0; n < 4; ++n) bf4[n] = bff[n0 + wn * 64 + n * 16 + ln];

    #pragma unroll
    for (int m = 0; m < 4; ++m)
        #pragma unroll
        for (int n = 0; n < 4; ++n)
            #pragma unroll
            for (int r = 0; r < 4; ++r) {
                int row = m0 + wm * 64 + m * 16 + hi * 4 + r;
                int col = n0 + wn * 64 + n * 16 + ln;
                size_t idx = (size_t)row * D + col;
                x2[idx] = x1[idx] + acc[m][n][r] + bf4[n];
            }
}

// ---------------------------------------------------------------------------
extern "C" void kernel_launch(void* const* d_in, const int* in_sizes, int n_in,
                              void* d_out, int out_size, void* d_ws, size_t ws_size,
                              hipStream_t stream)
{
    const float* x   = (const float*)d_in[0];
    const float* Wq  = (const float*)d_in[1];
    const float* bq  = (const float*)d_in[2];
    const float* Wk  = (const float*)d_in[3];
    const float* bk  = (const float*)d_in[4];
    const float* Wv  = (const float*)d_in[5];
    const float* bv  = (const float*)d_in[6];
    const float* Wff = (const float*)d_in[7];
    const float* bff = (const float*)d_in[8];
    float* out = (float*)d_out;

    const size_t NX = (size_t)BS * D;          // 4,194,304
    char* p = (char*)d_ws;
    auto alloc = [&](size_t bytes) { char* r = p; p += bytes; return r; };

    u16* xb    = (u16*)alloc(NX * 2);
    u16* WT    = (u16*)alloc((size_t)3 * H * DK * D * 2);   // [3072][1024]
    u16* WffT  = (u16*)alloc((size_t)D * D * 2);
    u16* Qw    = (u16*)alloc(NX * 2);
    u16* Kw    = (u16*)alloc(NX * 2);
    u16* Vtw   = (u16*)alloc(NX * 2);
    float* combined = (float*)alloc(NX * 4);
    float* x1       = (float*)alloc(NX * 4);
    u16*   x1b = xb;          // xb dead after qkv_gemm
    float* x2  = (float*)Qw;  // Qw+Kw dead after attn_pv

    convert_x<<<dim3(NX / 2048), 256, 0, stream>>>(x, xb);
    tconv3<<<dim3(1, 16, 48), 256, 0, stream>>>(Wq, Wk, Wv, WT);
    tconv<<<dim3(16, 16, 1), 256, 0, stream>>>(Wff, WffT, D, D);

    qkv_gemm<<<dim3(768), 256, 0, stream>>>(
        xb, WT, bq, bk, bv, Qw, Kw, Vtw);

    col_stats<<<dim3(1024), 256, 0, stream>>>(Qw, Kw, Vtw);

    attn_pv<<<dim3(1024), 256, 0, stream>>>(Qw, Kw, Vtw, combined);

    add_ln<<<BS, 256, 0, stream>>>(x, combined, x1, x1b);

    ffn<<<dim3(256), 256, 0, stream>>>(x1, x1b, WffT, bff, x2);

    add_ln<<<BS, 256, 0, stream>>>(x2, nullptr, out, nullptr);
}

// Round 17
// 143.824 us; speedup vs baseline: 1.0703x; 1.0283x over previous
//
#include <hip/hip_runtime.h>
#include <hip/hip_bf16.h>
#include <math.h>

typedef unsigned short u16;
typedef unsigned int u32;
typedef __attribute__((ext_vector_type(8))) short short8;
typedef __attribute__((ext_vector_type(4))) short short4v;
typedef __attribute__((ext_vector_type(4))) float f32x4;

constexpr int B  = 2;
constexpr int S  = 2048;
constexpr int D  = 1024;
constexpr int H  = 16;
constexpr int DK = 64;
constexpr int BS = B * S;   // 4096

__device__ __forceinline__ u16 f2b(float f) {
    __hip_bfloat16 h = __float2bfloat16(f);
    return *reinterpret_cast<u16*>(&h);
}
__device__ __forceinline__ float b2f(short s) {
    unsigned int u = ((unsigned int)(u16)s) << 16;
    return __builtin_bit_cast(float, u);
}

#define MFMA16(a, b, c) __builtin_amdgcn_mfma_f32_16x16x32_bf16((a), (b), (c), 0, 0, 0)

// async global->LDS, 16B per lane; LDS dest is wave-uniform base + lane*16
__device__ __forceinline__ void gload16(const u16* g, u16* l) {
    __builtin_amdgcn_global_load_lds(
        (const __attribute__((address_space(1))) u32*)g,
        (__attribute__((address_space(3))) u32*)l, 16, 0, 0);
}

// ---------------------------------------------------------------------------
// fp32 -> bf16 bulk convert (8 elements/thread)
// ---------------------------------------------------------------------------
__global__ __launch_bounds__(256) void convert_x(const float* __restrict__ src,
                                                 u16* __restrict__ dst)
{
    size_t i = ((size_t)blockIdx.x * 256 + threadIdx.x) * 8;
    f32x4 a = *reinterpret_cast<const f32x4*>(src + i);
    f32x4 b = *reinterpret_cast<const f32x4*>(src + i + 4);
    short8 o;
    o[0] = (short)f2b(a[0]); o[1] = (short)f2b(a[1]);
    o[2] = (short)f2b(a[2]); o[3] = (short)f2b(a[3]);
    o[4] = (short)f2b(b[0]); o[5] = (short)f2b(b[1]);
    o[6] = (short)f2b(b[2]); o[7] = (short)f2b(b[3]);
    *reinterpret_cast<short8*>(dst + i) = o;
}

// ---------------------------------------------------------------------------
// Tiled transpose + convert: src fp32 [batch][R][C] -> dst bf16 [batch][C][R]
// ---------------------------------------------------------------------------
__global__ __launch_bounds__(256) void tconv(const float* __restrict__ src,
                                             u16* __restrict__ dst, int R, int C)
{
    const int bb = blockIdx.z;
    src += (size_t)bb * R * C;
    dst += (size_t)bb * R * C;
    const int c0 = blockIdx.x * 64, r0 = blockIdx.y * 64;
    __shared__ float Ts[64][65];
    const int tid = threadIdx.x;
    #pragma unroll
    for (int i = 0; i < 4; ++i) {
        int idx = i * 1024 + tid * 4;
        int r = idx >> 6, c = idx & 63;
        f32x4 v = *reinterpret_cast<const f32x4*>(&src[(size_t)(r0 + r) * C + c0 + c]);
        Ts[r][c] = v[0]; Ts[r][c + 1] = v[1]; Ts[r][c + 2] = v[2]; Ts[r][c + 3] = v[3];
    }
    __syncthreads();
    #pragma unroll
    for (int i = 0; i < 4; ++i) {
        int cc = i * 16 + (tid >> 4);
        int rr = (tid & 15) * 4;
        short4v pk;
        pk[0] = (short)f2b(Ts[rr][cc]);     pk[1] = (short)f2b(Ts[rr + 1][cc]);
        pk[2] = (short)f2b(Ts[rr + 2][cc]); pk[3] = (short)f2b(Ts[rr + 3][cc]);
        *reinterpret_cast<short4v*>(&dst[(size_t)(c0 + cc) * R + r0 + rr]) = pk;
    }
}

// ---------------------------------------------------------------------------
// Combined transpose+convert for the 3 QKV weights -> WT [3072][1024].
// grid (1, 16, 48): z/16 selects Wq/Wk/Wv, z%16 is the head.
// ---------------------------------------------------------------------------
__global__ __launch_bounds__(256) void tconv3(
    const float* __restrict__ wq, const float* __restrict__ wk,
    const float* __restrict__ wv, u16* __restrict__ dst)
{
    const int z = blockIdx.z;
    const int selw = z >> 4, bb = z & 15;
    const float* src = selw == 0 ? wq : selw == 1 ? wk : wv;
    src += (size_t)bb * D * DK;
    u16* d = dst + (size_t)selw * H * DK * D + (size_t)bb * D * DK;
    const int r0 = blockIdx.y * 64;
    __shared__ float Ts[64][65];
    const int tid = threadIdx.x;
    #pragma unroll
    for (int i = 0; i < 4; ++i) {
        int idx = i * 1024 + tid * 4;
        int r = idx >> 6, c = idx & 63;
        f32x4 v = *reinterpret_cast<const f32x4*>(&src[(size_t)(r0 + r) * DK + c]);
        Ts[r][c] = v[0]; Ts[r][c + 1] = v[1]; Ts[r][c + 2] = v[2]; Ts[r][c + 3] = v[3];
    }
    __syncthreads();
    #pragma unroll
    for (int i = 0; i < 4; ++i) {
        int cc = i * 16 + (tid >> 4);
        int rr = (tid & 15) * 4;
        short4v pk;
        pk[0] = (short)f2b(Ts[rr][cc]);     pk[1] = (short)f2b(Ts[rr + 1][cc]);
        pk[2] = (short)f2b(Ts[rr + 2][cc]); pk[3] = (short)f2b(Ts[rr + 3][cc]);
        *reinterpret_cast<short4v*>(&d[(size_t)cc * D + r0 + rr]) = pk;
    }
}

// ---------------------------------------------------------------------------
// QKV projection as ONE 128x128-tile GEMM (global_load_lds staging, dbuf,
// pre-swizzled source columns).  Grid 768.
// ---------------------------------------------------------------------------
__global__ __launch_bounds__(256) void qkv_gemm(
    const u16* __restrict__ xb, const u16* __restrict__ WT,
    const float* __restrict__ bq, const float* __restrict__ bk, const float* __restrict__ bv,
    u16* __restrict__ Qw, u16* __restrict__ Kw, u16* __restrict__ Vtw)
{
    const int id   = blockIdx.x;
    const int xcd  = id & 7;
    const int j    = id >> 3;               // 0..95
    const int nblk = xcd * 3 + j % 3;       // 0..23
    const int mblk = j / 3;                 // 0..31
    const int m0 = mblk * 128, n0 = nblk * 128;
    const int sel = n0 >> 10;               // uniform per block
    const float* bias = sel == 0 ? bq : sel == 1 ? bk : bv;

    __shared__ u16 SM[2][2][128][64];       // [buf][A/B][row][col], 64KB

    const int tid = threadIdx.x;
    const int w = tid >> 6, ln = tid & 15, hi = (tid & 63) >> 4;
    const int wm = w >> 1, wn = w & 1;
    const int l  = tid & 63;
    const int lr = l >> 3;                  // row within 8-row chunk
    const int lc8 = ((l & 7) ^ lr) * 8;     // pre-swizzled source col (u16)

    char* sA0 = (char*)&SM[0][0][0][0];
    char* sB0 = (char*)&SM[0][1][0][0];
    char* sA1 = (char*)&SM[1][0][0][0];
    char* sB1 = (char*)&SM[1][1][0][0];
    auto swz = [](int r, int cb) { return r * 128 + (cb ^ ((r & 7) << 4)); };

    f32x4 acc[4][4];
    #pragma unroll
    for (int m = 0; m < 4; ++m)
        #pragma unroll
        for (int n = 0; n < 4; ++n) acc[m][n] = f32x4{0.f, 0.f, 0.f, 0.f};

    auto stage = [&](char* sa, char* sb, int k0) {
        #pragma unroll
        for (int c = 0; c < 4; ++c) {
            int rbase = w * 32 + c * 8;         // wave-uniform chunk base
            int row = rbase + lr;
            gload16(&xb[(size_t)(m0 + row) * D + k0 + lc8], (u16*)(sa + rbase * 128));
            gload16(&WT[(size_t)(n0 + row) * D + k0 + lc8], (u16*)(sb + rbase * 128));
        }
    };

    stage(sA0, sB0, 0);
    __syncthreads();

    for (int it = 0; it < 16; ++it) {
        char* ac = (it & 1) ? sA1 : sA0;
        char* bc = (it & 1) ? sB1 : sB0;
        if (it + 1 < 16)
            stage((it & 1) ? sA0 : sA1, (it & 1) ? sB0 : sB1, (it + 1) * 64);
        #pragma unroll
        for (int ks = 0; ks < 2; ++ks) {
            short8 af[4], bf[4];
            #pragma unroll
            for (int m = 0; m < 4; ++m)
                af[m] = *reinterpret_cast<const short8*>(
                    ac + swz(wm * 64 + m * 16 + ln, ks * 64 + hi * 16));
            #pragma unroll
            for (int n = 0; n < 4; ++n)
                bf[n] = *reinterpret_cast<const short8*>(
                    bc + swz(wn * 64 + n * 16 + ln, ks * 64 + hi * 16));
            #pragma unroll
            for (int m = 0; m < 4; ++m)
                #pragma unroll
                for (int n = 0; n < 4; ++n)
                    acc[m][n] = MFMA16(af[m], bf[n], acc[m][n]);
        }
        __syncthreads();   // drains prefetch (vmcnt) + read-done for overwrite
    }

    float bias4[4];
    #pragma unroll
    for (int n = 0; n < 4; ++n)
        bias4[n] = bias[(n0 & 1023) + wn * 64 + n * 16 + ln];

    // epilogue via 32KB swizzled LDS region (SM[0])
    char* eb = sA0;
    const int bidx  = m0 >> 11;
    const int sbase = m0 & 2047;
    const int h0    = (n0 & 1023) >> 6;

    if (sel < 2) {
        #pragma unroll
        for (int m = 0; m < 4; ++m)
            #pragma unroll
            for (int n = 0; n < 4; ++n)
                #pragma unroll
                for (int r = 0; r < 4; ++r) {
                    int row = wm * 64 + m * 16 + hi * 4 + r;
                    int col = wn * 64 + n * 16 + ln;
                    *reinterpret_cast<u16*>(eb + row * 256 + ((col * 2) ^ ((row & 7) << 4))) =
                        f2b(acc[m][n][r] + bias4[n]);
                }
        __syncthreads();
        u16* dst0 = sel == 0 ? Qw : Kw;
        #pragma unroll
        for (int c = 0; c < 8; ++c) {
            int idx = c * 256 + tid;
            int row = idx >> 4, g = idx & 15;
            short8 v = *reinterpret_cast<const short8*>(
                eb + row * 256 + ((g * 16) ^ ((row & 7) << 4)));
            int h = h0 + (g >> 3), j0 = (g & 7) * 8;
            *reinterpret_cast<short8*>(
                &dst0[((size_t)(bidx * H + h) * S + sbase + row) * DK + j0]) = v;
        }
    } else {
        #pragma unroll
        for (int m = 0; m < 4; ++m)
            #pragma unroll
            for (int n = 0; n < 4; ++n)
                #pragma unroll
                for (int r = 0; r < 4; ++r) {
                    int row = wm * 64 + m * 16 + hi * 4 + r;   // s
                    int col = wn * 64 + n * 16 + ln;           // e (2 heads)
                    *reinterpret_cast<u16*>(eb + col * 256 + ((row * 2) ^ ((col & 7) << 4))) =
                        f2b(acc[m][n][r] + bias4[n]);
                }
        __syncthreads();
        #pragma unroll
        for (int c = 0; c < 8; ++c) {
            int idx = c * 256 + tid;
            int e = idx >> 4, g = idx & 15;
            short8 v = *reinterpret_cast<const short8*>(
                eb + e * 256 + ((g * 16) ^ ((e & 7) << 4)));
            int h = h0 + (e >> 6), ein = e & 63;
            *reinterpret_cast<short8*>(
                &Vtw[((size_t)(bidx * H + h) * DK + ein) * S + sbase + g * 8]) = v;
        }
    }
}

// ---------------------------------------------------------------------------
// Column softmax denominator + fold 1/Z into V (in place).  Round-9 form:
// grid 1024, XCD-swizzled, descending t0 (heaviest first).
// ---------------------------------------------------------------------------
__global__ __launch_bounds__(256) void col_stats(
    const u16* __restrict__ Qw, const u16* __restrict__ Kw,
    u16* __restrict__ Vtw)
{
    const int id = blockIdx.x;
    const int bh = (id & 7) * 4 + ((id >> 3) & 3);
    const int t0 = (31 - (id >> 5)) * 64;       // descending work (LPT)
    const u16* Qh = Qw + (size_t)bh * S * DK;
    const u16* Kh = Kw + (size_t)bh * S * DK;
    u16* Vh = Vtw + (size_t)bh * DK * S;

    __shared__ u16 Qs[2][64][64];
    __shared__ float zbuf[64];

    const int tid = threadIdx.x;
    const int w = tid >> 6, ln = tid & 15, hi = (tid & 63) >> 4;
    const int e0 = tid >> 3, sc = tid & 7;

    char* qb0 = (char*)&Qs[0][0][0];
    char* qb1 = (char*)&Qs[1][0][0];
    auto swz = [](int row, int colb) { return (row * 128 + colb) ^ ((row & 7) << 4); };

    short8 ak[2];
    #pragma unroll
    for (int ks = 0; ks < 2; ++ks)
        ak[ks] = *reinterpret_cast<const short8*>(
            &Kh[(size_t)(t0 + w * 16 + ln) * DK + ks * 32 + hi * 8]);

    float zs[4] = {0.f, 0.f, 0.f, 0.f};

    {
        short8 a = *reinterpret_cast<const short8*>(&Qh[(size_t)e0 * DK + sc * 8]);
        short8 b = *reinterpret_cast<const short8*>(&Qh[(size_t)(e0 + 32) * DK + sc * 8]);
        *reinterpret_cast<short8*>(qb0 + swz(e0, sc * 16)) = a;
        *reinterpret_cast<short8*>(qb0 + swz(e0 + 32, sc * 16)) = b;
    }
    __syncthreads();

    int cur = 0;
    for (int s0b = 0; s0b <= t0; s0b += 64) {
        const bool nxt = (s0b + 64 <= t0);
        short8 nq0, nq1;
        if (nxt) {
            nq0 = *reinterpret_cast<const short8*>(&Qh[(size_t)(s0b + 64 + e0) * DK + sc * 8]);
            nq1 = *reinterpret_cast<const short8*>(&Qh[(size_t)(s0b + 96 + e0) * DK + sc * 8]);
        }
        char* qb = cur ? qb1 : qb0;
        f32x4 c[4];
        #pragma unroll
        for (int n = 0; n < 4; ++n) c[n] = f32x4{0.f, 0.f, 0.f, 0.f};
        #pragma unroll
        for (int ks = 0; ks < 2; ++ks)
            #pragma unroll
            for (int n = 0; n < 4; ++n) {
                short8 bqf = *reinterpret_cast<const short8*>(
                    qb + swz(n * 16 + ln, ks * 64 + hi * 16));
                c[n] = MFMA16(ak[ks], bqf, c[n]);
            }
        if (s0b == t0) {
            #pragma unroll
            for (int n = 0; n < 4; ++n)
                #pragma unroll
                for (int r = 0; r < 4; ++r)
                    if (s0b + n * 16 + ln > t0 + w * 16 + hi * 4 + r)
                        c[n][r] = -INFINITY;
        }
        #pragma unroll
        for (int n = 0; n < 4; ++n)
            #pragma unroll
            for (int r = 0; r < 4; ++r)
                zs[r] += __expf(c[n][r]);
        if (nxt) {
            char* qn = cur ? qb0 : qb1;
            *reinterpret_cast<short8*>(qn + swz(e0, sc * 16)) = nq0;
            *reinterpret_cast<short8*>(qn + swz(e0 + 32, sc * 16)) = nq1;
        }
        __syncthreads();
        cur ^= 1;
    }

    #pragma unroll
    for (int r = 0; r < 4; ++r) {
        #pragma unroll
        for (int msk = 1; msk < 16; msk <<= 1)
            zs[r] += __shfl_xor(zs[r], msk, 64);
    }
    if (ln == 0) {
        #pragma unroll
        for (int r = 0; r < 4; ++r)
            zbuf[w * 16 + hi * 4 + r] = 1.f / zs[r];
    }
    __syncthreads();

    float iz[8];
    #pragma unroll
    for (int j = 0; j < 8; ++j) iz[j] = zbuf[sc * 8 + j];
    #pragma unroll
    for (int pass = 0; pass < 2; ++pass) {
        int e = e0 + 32 * pass;
        u16* vp = &Vh[(size_t)e * S + t0 + sc * 8];
        short8 v = *reinterpret_cast<short8*>(vp);
        short8 o;
        #pragma unroll
        for (int j = 0; j < 8; ++j) o[j] = (short)f2b(b2f(v[j]) * iz[j]);
        *reinterpret_cast<short8*>(vp) = o;
    }
}

// ---------------------------------------------------------------------------
// P.V with V pre-scaled by 1/Z (P = raw exp).  Round-9 form: grid 1024,
// XCD-swizzled; V reg-staged into LDS dbuf; K reg ping-pong; 2 barriers/tile.
// ---------------------------------------------------------------------------
__global__ __launch_bounds__(256) void attn_pv(
    const u16* __restrict__ Qw, const u16* __restrict__ Kw, const u16* __restrict__ Vtw,
    float* __restrict__ combined)
{
    const int id = blockIdx.x;
    const int bh = (id & 7) * 4 + ((id >> 3) & 3);
    const int s0 = (id >> 5) * 64;              // s0=0 (most work) first
    const int bidx = bh >> 4, h = bh & 15;
    const u16* Qh = Qw + (size_t)bh * S * DK;
    const u16* Kh = Kw + (size_t)bh * S * DK;
    const u16* Vh = Vtw + (size_t)bh * DK * S;

    __shared__ u16 Vs[2][64][64];
    __shared__ u16 Ps[64][72];

    const int tid = threadIdx.x;
    const int w = tid >> 6, ln = tid & 15, hi = (tid & 63) >> 4;
    const int e0 = tid >> 3, sc = tid & 7;

    char* vb0 = (char*)&Vs[0][0][0];
    char* vb1 = (char*)&Vs[1][0][0];
    auto swz = [](int row, int colb) { return (row * 128 + colb) ^ ((row & 7) << 4); };

    short8 bq[4][2];
    #pragma unroll
    for (int n = 0; n < 4; ++n)
        #pragma unroll
        for (int ks = 0; ks < 2; ++ks)
            bq[n][ks] = *reinterpret_cast<const short8*>(
                &Qh[(size_t)(s0 + n * 16 + ln) * DK + ks * 32 + hi * 8]);

    f32x4 acc[4];
    #pragma unroll
    for (int n = 0; n < 4; ++n) acc[n] = f32x4{0.f, 0.f, 0.f, 0.f};

    {
        short8 a = *reinterpret_cast<const short8*>(&Vh[(size_t)e0 * S + s0 + sc * 8]);
        short8 b = *reinterpret_cast<const short8*>(&Vh[(size_t)(e0 + 32) * S + s0 + sc * 8]);
        *reinterpret_cast<short8*>(vb0 + swz(e0, sc * 16)) = a;
        *reinterpret_cast<short8*>(vb0 + swz(e0 + 32, sc * 16)) = b;
    }

    short8 akA[2], akB[2];
    auto loadK = [&](short8 (&ak)[2], int t1) {
        #pragma unroll
        for (int ks = 0; ks < 2; ++ks)
            ak[ks] = *reinterpret_cast<const short8*>(
                &Kh[(size_t)(t1 + w * 16 + ln) * DK + ks * 32 + hi * 8]);
    };

    loadK(akA, s0);
    __syncthreads();
    int cur = 0;

    auto tile = [&](short8 (&ak)[2], int t1) {
        const bool nxt = (t1 + 64 < S);
        short8 nv0, nv1;
        if (nxt) {
            nv0 = *reinterpret_cast<const short8*>(&Vh[(size_t)e0 * S + t1 + 64 + sc * 8]);
            nv1 = *reinterpret_cast<const short8*>(&Vh[(size_t)(e0 + 32) * S + t1 + 64 + sc * 8]);
        }

        f32x4 st[4];
        #pragma unroll
        for (int n = 0; n < 4; ++n) st[n] = f32x4{0.f, 0.f, 0.f, 0.f};
        #pragma unroll
        for (int ks = 0; ks < 2; ++ks)
            #pragma unroll
            for (int n = 0; n < 4; ++n)
                st[n] = MFMA16(ak[ks], bq[n][ks], st[n]);

        const bool diag = (t1 == s0);
        #pragma unroll
        for (int n = 0; n < 4; ++n) {
            short4v pk;
            #pragma unroll
            for (int r = 0; r < 4; ++r) {
                float p = __expf(st[n][r]);
                if (diag && (s0 + n * 16 + ln) > (t1 + w * 16 + hi * 4 + r)) p = 0.f;
                pk[r] = (short)f2b(p);
            }
            *reinterpret_cast<short4v*>(&Ps[n * 16 + ln][w * 16 + hi * 4]) = pk;
        }
        __syncthreads();   // P visible to all waves

        char* vb = cur ? vb1 : vb0;
        short8 pa[2];
        #pragma unroll
        for (int ks = 0; ks < 2; ++ks)
            pa[ks] = *reinterpret_cast<const short8*>(&Ps[w * 16 + ln][ks * 32 + hi * 8]);
        #pragma unroll
        for (int ks = 0; ks < 2; ++ks)
            #pragma unroll
            for (int n = 0; n < 4; ++n) {
                short8 vv = *reinterpret_cast<const short8*>(
                    vb + swz(n * 16 + ln, ks * 64 + hi * 16));
                acc[n] = MFMA16(pa[ks], vv, acc[n]);
            }

        if (nxt) {
            char* vn = cur ? vb0 : vb1;
            *reinterpret_cast<short8*>(vn + swz(e0, sc * 16)) = nv0;
            *reinterpret_cast<short8*>(vn + swz(e0 + 32, sc * 16)) = nv1;
        }
        __syncthreads();   // P consumed; next V staged
        cur ^= 1;
    };

    int t1 = s0;
    while (t1 < S) {
        if (t1 + 64 < S) loadK(akB, t1 + 64);
        tile(akA, t1);
        t1 += 64;
        if (t1 >= S) break;
        if (t1 + 64 < S) loadK(akA, t1 + 64);
        tile(akB, t1);
        t1 += 64;
    }

    #pragma unroll
    for (int n = 0; n < 4; ++n)
        #pragma unroll
        for (int r = 0; r < 4; ++r) {
            int s = s0 + w * 16 + hi * 4 + r;
            combined[((size_t)bidx * S + s) * D + h * DK + n * 16 + ln] = acc[n][r];
        }
}

// ---------------------------------------------------------------------------
// x1b = bf16(layernorm(a + bsrc)) — fp32 output elided (ffn reads bf16).
// ---------------------------------------------------------------------------
__global__ __launch_bounds__(256) void add_ln_b(
    const float* __restrict__ a, const float* __restrict__ bsrc,
    u16* __restrict__ outb)
{
    const int row = blockIdx.x;
    const int tid = threadIdx.x;
    const size_t base = (size_t)row * D;

    float v[4];
    float sum = 0.f;
    #pragma unroll
    for (int i = 0; i < 4; ++i) {
        int c = tid + i * 256;
        float t = a[base + c] + bsrc[base + c];
        v[i] = t;
        sum += t;
    }

    __shared__ float red[8];
    #pragma unroll
    for (int o = 32; o > 0; o >>= 1) sum += __shfl_down(sum, o, 64);
    const int lane = tid & 63, w = tid >> 6;
    if (lane == 0) red[w] = sum;
    __syncthreads();
    const float mean = (red[0] + red[1] + red[2] + red[3]) * (1.f / D);

    float s2 = 0.f;
    #pragma unroll
    for (int i = 0; i < 4; ++i) { float d2 = v[i] - mean; s2 += d2 * d2; }
    #pragma unroll
    for (int o = 32; o > 0; o >>= 1) s2 += __shfl_down(s2, o, 64);
    if (lane == 0) red[4 + w] = s2;
    __syncthreads();
    const float var = (red[4] + red[5] + red[6] + red[7]) * (1.f / (D - 1));
    const float scale = 1.f / (sqrtf(var) + 1e-4f);

    #pragma unroll
    for (int i = 0; i < 4; ++i) {
        int c = tid + i * 256;
        outb[base + c] = f2b((v[i] - mean) * scale);
    }
}

// ---------------------------------------------------------------------------
// out = layernorm(a) with bf16 input — final LN.
// ---------------------------------------------------------------------------
__global__ __launch_bounds__(256) void ln_final(
    const u16* __restrict__ a, float* __restrict__ out)
{
    const int row = blockIdx.x;
    const int tid = threadIdx.x;
    const size_t base = (size_t)row * D;

    float v[4];
    float sum = 0.f;
    #pragma unroll
    for (int i = 0; i < 4; ++i) {
        int c = tid + i * 256;
        v[i] = b2f(a[base + c]);
        sum += v[i];
    }

    __shared__ float red[8];
    #pragma unroll
    for (int o = 32; o > 0; o >>= 1) sum += __shfl_down(sum, o, 64);
    const int lane = tid & 63, w = tid >> 6;
    if (lane == 0) red[w] = sum;
    __syncthreads();
    const float mean = (red[0] + red[1] + red[2] + red[3]) * (1.f / D);

    float s2 = 0.f;
    #pragma unroll
    for (int i = 0; i < 4; ++i) { float d2 = v[i] - mean; s2 += d2 * d2; }
    #pragma unroll
    for (int o = 32; o > 0; o >>= 1) s2 += __shfl_down(s2, o, 64);
    if (lane == 0) red[4 + w] = s2;
    __syncthreads();
    const float var = (red[4] + red[5] + red[6] + red[7]) * (1.f / (D - 1));
    const float scale = 1.f / (sqrtf(var) + 1e-4f);

    #pragma unroll
    for (int i = 0; i < 4; ++i) {
        int c = tid + i * 256;
        out[base + c] = (v[i] - mean) * scale;
    }
}

// ---------------------------------------------------------------------------
// FFN: x2b = bf16(x1 + x1b @ WffT^T + bff), residual read from bf16 x1b.
// 1D grid 256, XCD-swizzled.  global_load_lds + pre-swizzled-source + dbuf.
// ---------------------------------------------------------------------------
__global__ __launch_bounds__(256) void ffn(
    const u16* __restrict__ x1b, const u16* __restrict__ WffT,
    const float* __restrict__ bff, u16* __restrict__ x2b)
{
    const int id = blockIdx.x;
    const int m0 = ((id & 7) * 4 + ((id >> 3) & 3)) * 128;
    const int n0 = (id >> 5) * 128;

    __shared__ u16 SM[2][2][128][64];       // [buf][A/B][row][col], 64KB

    const int tid = threadIdx.x;
    const int w = tid >> 6, ln = tid & 15, hi = (tid & 63) >> 4;
    const int wm = w >> 1, wn = w & 1;
    const int l  = tid & 63;
    const int lr = l >> 3;
    const int lc8 = ((l & 7) ^ lr) * 8;

    char* sA0 = (char*)&SM[0][0][0][0];
    char* sB0 = (char*)&SM[0][1][0][0];
    char* sA1 = (char*)&SM[1][0][0][0];
    char* sB1 = (char*)&SM[1][1][0][0];
    auto swz = [](int r, int cb) { return r * 128 + (cb ^ ((r & 7) << 4)); };

    f32x4 acc[4][4];
    #pragma unroll
    for (int m = 0; m < 4; ++m)
        #pragma unroll
        for (int n = 0; n < 4; ++n) acc[m][n] = f32x4{0.f, 0.f, 0.f, 0.f};

    auto stage = [&](char* sa, char* sb, int k0) {
        #pragma unroll
        for (int c = 0; c < 4; ++c) {
            int rbase = w * 32 + c * 8;
            int row = rbase + lr;
            gload16(&x1b[(size_t)(m0 + row) * D + k0 + lc8], (u16*)(sa + rbase * 128));
            gload16(&WffT[(size_t)(n0 + row) * D + k0 + lc8], (u16*)(sb + rbase * 128));
        }
    };

    stage(sA0, sB0, 0);
    __syncthreads();

    for (int it = 0; it < 16; ++it) {
        char* ac = (it & 1) ? sA1 : sA0;
        char* bc = (it & 1) ? sB1 : sB0;
        if (it + 1 < 16)
            stage((it & 1) ? sA0 : sA1, (it & 1) ? sB0 : sB1, (it + 1) * 64);
        #pragma unroll
        for (int ks = 0; ks < 2; ++ks) {
            short8 af[4], bf[4];
            #pragma unroll
            for (int m = 0; m < 4; ++m)
                af[m] = *reinterpret_cast<const short8*>(
                    ac + swz(wm * 64 + m * 16 + ln, ks * 64 + hi * 16));
            #pragma unroll
            for (int n = 0; n < 4; ++n)
                bf[n] = *reinterpret_cast<const short8*>(
                    bc + swz(wn * 64 + n * 16 + ln, ks * 64 + hi * 16));
            #pragma unroll
            for (int m = 0; m < 4; ++m)
                #pragma unroll
                for (int n = 0; n < 4; ++n)
                    acc[m][n] = MFMA16(af[m], bf[n], acc[m][n]);
        }
        __syncthreads();
    }

    float bf4[4];
    #pragma unroll
    for (int n = 0; n < 4; ++n) bf4[n] = bff[n0 + wn * 64 + n * 16 + ln];

    #pragma unroll
    for (int m = 0; m < 4; ++m)
        #pragma unroll
        for (int n = 0; n < 4; ++n)
            #pragma unroll
            for (int r = 0; r < 4; ++r) {
                int row = m0 + wm * 64 + m * 16 + hi * 4 + r;
                int col = n0 + wn * 64 + n * 16 + ln;
                size_t idx = (size_t)row * D + col;
                float xres = b2f(x1b[idx]);
                x2b[idx] = f2b(xres + acc[m][n][r] + bf4[n]);
            }
}

// ---------------------------------------------------------------------------
extern "C" void kernel_launch(void* const* d_in, const int* in_sizes, int n_in,
                              void* d_out, int out_size, void* d_ws, size_t ws_size,
                              hipStream_t stream)
{
    const float* x   = (const float*)d_in[0];
    const float* Wq  = (const float*)d_in[1];
    const float* bq  = (const float*)d_in[2];
    const float* Wk  = (const float*)d_in[3];
    const float* bk  = (const float*)d_in[4];
    const float* Wv  = (const float*)d_in[5];
    const float* bv  = (const float*)d_in[6];
    const float* Wff = (const float*)d_in[7];
    const float* bff = (const float*)d_in[8];
    float* out = (float*)d_out;

    const size_t NX = (size_t)BS * D;          // 4,194,304
    char* p = (char*)d_ws;
    auto alloc = [&](size_t bytes) { char* r = p; p += bytes; return r; };

    u16* xb    = (u16*)alloc(NX * 2);
    u16* WT    = (u16*)alloc((size_t)3 * H * DK * D * 2);   // [3072][1024]
    u16* WffT  = (u16*)alloc((size_t)D * D * 2);
    u16* Qw    = (u16*)alloc(NX * 2);
    u16* Kw    = (u16*)alloc(NX * 2);
    u16* Vtw   = (u16*)alloc(NX * 2);
    float* combined = (float*)alloc(NX * 4);
    u16*   x1b = xb;          // xb dead after qkv_gemm
    u16*   x2b = Qw;          // Qw dead after attn_pv

    convert_x<<<dim3(NX / 2048), 256, 0, stream>>>(x, xb);
    tconv3<<<dim3(1, 16, 48), 256, 0, stream>>>(Wq, Wk, Wv, WT);
    tconv<<<dim3(16, 16, 1), 256, 0, stream>>>(Wff, WffT, D, D);

    qkv_gemm<<<dim3(768), 256, 0, stream>>>(
        xb, WT, bq, bk, bv, Qw, Kw, Vtw);

    col_stats<<<dim3(1024), 256, 0, stream>>>(Qw, Kw, Vtw);

    attn_pv<<<dim3(1024), 256, 0, stream>>>(Qw, Kw, Vtw, combined);

    add_ln_b<<<BS, 256, 0, stream>>>(x, combined, x1b);

    ffn<<<dim3(256), 256, 0, stream>>>(x1b, WffT, bff, x2b);

    ln_final<<<BS, 256, 0, stream>>>(x2b, out);
}

// Round 18
// 143.152 us; speedup vs baseline: 1.0753x; 1.0047x over previous
//
#include <hip/hip_runtime.h>
#include <hip/hip_bf16.h>
#include <math.h>

typedef unsigned short u16;
typedef unsigned int u32;
typedef __attribute__((ext_vector_type(8))) short short8;
typedef __attribute__((ext_vector_type(4))) short short4v;
typedef __attribute__((ext_vector_type(4))) float f32x4;

constexpr int B  = 2;
constexpr int S  = 2048;
constexpr int D  = 1024;
constexpr int H  = 16;
constexpr int DK = 64;
constexpr int BS = B * S;   // 4096

__device__ __forceinline__ u16 f2b(float f) {
    __hip_bfloat16 h = __float2bfloat16(f);
    return *reinterpret_cast<u16*>(&h);
}
__device__ __forceinline__ float b2f(short s) {
    unsigned int u = ((unsigned int)(u16)s) << 16;
    return __builtin_bit_cast(float, u);
}

#define MFMA16(a, b, c) __builtin_amdgcn_mfma_f32_16x16x32_bf16((a), (b), (c), 0, 0, 0)

// async global->LDS, 16B per lane; LDS dest is wave-uniform base + lane*16
__device__ __forceinline__ void gload16(const u16* g, u16* l) {
    __builtin_amdgcn_global_load_lds(
        (const __attribute__((address_space(1))) u32*)g,
        (__attribute__((address_space(3))) u32*)l, 16, 0, 0);
}

// ---------------------------------------------------------------------------
// fp32 -> bf16 bulk convert (8 elements/thread)
// ---------------------------------------------------------------------------
__global__ __launch_bounds__(256) void convert_x(const float* __restrict__ src,
                                                 u16* __restrict__ dst)
{
    size_t i = ((size_t)blockIdx.x * 256 + threadIdx.x) * 8;
    f32x4 a = *reinterpret_cast<const f32x4*>(src + i);
    f32x4 b = *reinterpret_cast<const f32x4*>(src + i + 4);
    short8 o;
    o[0] = (short)f2b(a[0]); o[1] = (short)f2b(a[1]);
    o[2] = (short)f2b(a[2]); o[3] = (short)f2b(a[3]);
    o[4] = (short)f2b(b[0]); o[5] = (short)f2b(b[1]);
    o[6] = (short)f2b(b[2]); o[7] = (short)f2b(b[3]);
    *reinterpret_cast<short8*>(dst + i) = o;
}

// ---------------------------------------------------------------------------
// Tiled transpose + convert: src fp32 [batch][R][C] -> dst bf16 [batch][C][R]
// ---------------------------------------------------------------------------
__global__ __launch_bounds__(256) void tconv(const float* __restrict__ src,
                                             u16* __restrict__ dst, int R, int C)
{
    const int bb = blockIdx.z;
    src += (size_t)bb * R * C;
    dst += (size_t)bb * R * C;
    const int c0 = blockIdx.x * 64, r0 = blockIdx.y * 64;
    __shared__ float Ts[64][65];
    const int tid = threadIdx.x;
    #pragma unroll
    for (int i = 0; i < 4; ++i) {
        int idx = i * 1024 + tid * 4;
        int r = idx >> 6, c = idx & 63;
        f32x4 v = *reinterpret_cast<const f32x4*>(&src[(size_t)(r0 + r) * C + c0 + c]);
        Ts[r][c] = v[0]; Ts[r][c + 1] = v[1]; Ts[r][c + 2] = v[2]; Ts[r][c + 3] = v[3];
    }
    __syncthreads();
    #pragma unroll
    for (int i = 0; i < 4; ++i) {
        int cc = i * 16 + (tid >> 4);
        int rr = (tid & 15) * 4;
        short4v pk;
        pk[0] = (short)f2b(Ts[rr][cc]);     pk[1] = (short)f2b(Ts[rr + 1][cc]);
        pk[2] = (short)f2b(Ts[rr + 2][cc]); pk[3] = (short)f2b(Ts[rr + 3][cc]);
        *reinterpret_cast<short4v*>(&dst[(size_t)(c0 + cc) * R + r0 + rr]) = pk;
    }
}

// ---------------------------------------------------------------------------
// Combined transpose+convert for the 3 QKV weights -> WT [3072][1024].
// grid (1, 16, 48): z/16 selects Wq/Wk/Wv, z%16 is the head.
// ---------------------------------------------------------------------------
__global__ __launch_bounds__(256) void tconv3(
    const float* __restrict__ wq, const float* __restrict__ wk,
    const float* __restrict__ wv, u16* __restrict__ dst)
{
    const int z = blockIdx.z;
    const int selw = z >> 4, bb = z & 15;
    const float* src = selw == 0 ? wq : selw == 1 ? wk : wv;
    src += (size_t)bb * D * DK;
    u16* d = dst + (size_t)selw * H * DK * D + (size_t)bb * D * DK;
    const int r0 = blockIdx.y * 64;
    __shared__ float Ts[64][65];
    const int tid = threadIdx.x;
    #pragma unroll
    for (int i = 0; i < 4; ++i) {
        int idx = i * 1024 + tid * 4;
        int r = idx >> 6, c = idx & 63;
        f32x4 v = *reinterpret_cast<const f32x4*>(&src[(size_t)(r0 + r) * DK + c]);
        Ts[r][c] = v[0]; Ts[r][c + 1] = v[1]; Ts[r][c + 2] = v[2]; Ts[r][c + 3] = v[3];
    }
    __syncthreads();
    #pragma unroll
    for (int i = 0; i < 4; ++i) {
        int cc = i * 16 + (tid >> 4);
        int rr = (tid & 15) * 4;
        short4v pk;
        pk[0] = (short)f2b(Ts[rr][cc]);     pk[1] = (short)f2b(Ts[rr + 1][cc]);
        pk[2] = (short)f2b(Ts[rr + 2][cc]); pk[3] = (short)f2b(Ts[rr + 3][cc]);
        *reinterpret_cast<short4v*>(&d[(size_t)cc * D + r0 + rr]) = pk;
    }
}

// ---------------------------------------------------------------------------
// QKV projection as ONE 128x128-tile GEMM (global_load_lds staging, dbuf,
// pre-swizzled source columns).  Grid 768.
// ---------------------------------------------------------------------------
__global__ __launch_bounds__(256) void qkv_gemm(
    const u16* __restrict__ xb, const u16* __restrict__ WT,
    const float* __restrict__ bq, const float* __restrict__ bk, const float* __restrict__ bv,
    u16* __restrict__ Qw, u16* __restrict__ Kw, u16* __restrict__ Vtw)
{
    const int id   = blockIdx.x;
    const int xcd  = id & 7;
    const int j    = id >> 3;               // 0..95
    const int nblk = xcd * 3 + j % 3;       // 0..23
    const int mblk = j / 3;                 // 0..31
    const int m0 = mblk * 128, n0 = nblk * 128;
    const int sel = n0 >> 10;               // uniform per block
    const float* bias = sel == 0 ? bq : sel == 1 ? bk : bv;

    __shared__ u16 SM[2][2][128][64];       // [buf][A/B][row][col], 64KB

    const int tid = threadIdx.x;
    const int w = tid >> 6, ln = tid & 15, hi = (tid & 63) >> 4;
    const int wm = w >> 1, wn = w & 1;
    const int l  = tid & 63;
    const int lr = l >> 3;                  // row within 8-row chunk
    const int lc8 = ((l & 7) ^ lr) * 8;     // pre-swizzled source col (u16)

    char* sA0 = (char*)&SM[0][0][0][0];
    char* sB0 = (char*)&SM[0][1][0][0];
    char* sA1 = (char*)&SM[1][0][0][0];
    char* sB1 = (char*)&SM[1][1][0][0];
    auto swz = [](int r, int cb) { return r * 128 + (cb ^ ((r & 7) << 4)); };

    f32x4 acc[4][4];
    #pragma unroll
    for (int m = 0; m < 4; ++m)
        #pragma unroll
        for (int n = 0; n < 4; ++n) acc[m][n] = f32x4{0.f, 0.f, 0.f, 0.f};

    auto stage = [&](char* sa, char* sb, int k0) {
        #pragma unroll
        for (int c = 0; c < 4; ++c) {
            int rbase = w * 32 + c * 8;         // wave-uniform chunk base
            int row = rbase + lr;
            gload16(&xb[(size_t)(m0 + row) * D + k0 + lc8], (u16*)(sa + rbase * 128));
            gload16(&WT[(size_t)(n0 + row) * D + k0 + lc8], (u16*)(sb + rbase * 128));
        }
    };

    stage(sA0, sB0, 0);
    __syncthreads();

    for (int it = 0; it < 16; ++it) {
        char* ac = (it & 1) ? sA1 : sA0;
        char* bc = (it & 1) ? sB1 : sB0;
        if (it + 1 < 16)
            stage((it & 1) ? sA0 : sA1, (it & 1) ? sB0 : sB1, (it + 1) * 64);
        #pragma unroll
        for (int ks = 0; ks < 2; ++ks) {
            short8 af[4], bf[4];
            #pragma unroll
            for (int m = 0; m < 4; ++m)
                af[m] = *reinterpret_cast<const short8*>(
                    ac + swz(wm * 64 + m * 16 + ln, ks * 64 + hi * 16));
            #pragma unroll
            for (int n = 0; n < 4; ++n)
                bf[n] = *reinterpret_cast<const short8*>(
                    bc + swz(wn * 64 + n * 16 + ln, ks * 64 + hi * 16));
            #pragma unroll
            for (int m = 0; m < 4; ++m)
                #pragma unroll
                for (int n = 0; n < 4; ++n)
                    acc[m][n] = MFMA16(af[m], bf[n], acc[m][n]);
        }
        __syncthreads();   // drains prefetch (vmcnt) + read-done for overwrite
    }

    float bias4[4];
    #pragma unroll
    for (int n = 0; n < 4; ++n)
        bias4[n] = bias[(n0 & 1023) + wn * 64 + n * 16 + ln];

    // epilogue via 32KB swizzled LDS region (SM[0])
    char* eb = sA0;
    const int bidx  = m0 >> 11;
    const int sbase = m0 & 2047;
    const int h0    = (n0 & 1023) >> 6;

    if (sel < 2) {
        #pragma unroll
        for (int m = 0; m < 4; ++m)
            #pragma unroll
            for (int n = 0; n < 4; ++n)
                #pragma unroll
                for (int r = 0; r < 4; ++r) {
                    int row = wm * 64 + m * 16 + hi * 4 + r;
                    int col = wn * 64 + n * 16 + ln;
                    *reinterpret_cast<u16*>(eb + row * 256 + ((col * 2) ^ ((row & 7) << 4))) =
                        f2b(acc[m][n][r] + bias4[n]);
                }
        __syncthreads();
        u16* dst0 = sel == 0 ? Qw : Kw;
        #pragma unroll
        for (int c = 0; c < 8; ++c) {
            int idx = c * 256 + tid;
            int row = idx >> 4, g = idx & 15;
            short8 v = *reinterpret_cast<const short8*>(
                eb + row * 256 + ((g * 16) ^ ((row & 7) << 4)));
            int h = h0 + (g >> 3), j0 = (g & 7) * 8;
            *reinterpret_cast<short8*>(
                &dst0[((size_t)(bidx * H + h) * S + sbase + row) * DK + j0]) = v;
        }
    } else {
        #pragma unroll
        for (int m = 0; m < 4; ++m)
            #pragma unroll
            for (int n = 0; n < 4; ++n)
                #pragma unroll
                for (int r = 0; r < 4; ++r) {
                    int row = wm * 64 + m * 16 + hi * 4 + r;   // s
                    int col = wn * 64 + n * 16 + ln;           // e (2 heads)
                    *reinterpret_cast<u16*>(eb + col * 256 + ((row * 2) ^ ((col & 7) << 4))) =
                        f2b(acc[m][n][r] + bias4[n]);
                }
        __syncthreads();
        #pragma unroll
        for (int c = 0; c < 8; ++c) {
            int idx = c * 256 + tid;
            int e = idx >> 4, g = idx & 15;
            short8 v = *reinterpret_cast<const short8*>(
                eb + e * 256 + ((g * 16) ^ ((e & 7) << 4)));
            int h = h0 + (e >> 6), ein = e & 63;
            *reinterpret_cast<short8*>(
                &Vtw[((size_t)(bidx * H + h) * DK + ein) * S + sbase + g * 8]) = v;
        }
    }
}

// ---------------------------------------------------------------------------
// Column softmax denominator + fold 1/Z into V (in place).  Round-9 form:
// grid 1024, XCD-swizzled, descending t0 (heaviest first).
// ---------------------------------------------------------------------------
__global__ __launch_bounds__(256) void col_stats(
    const u16* __restrict__ Qw, const u16* __restrict__ Kw,
    u16* __restrict__ Vtw)
{
    const int id = blockIdx.x;
    const int bh = (id & 7) * 4 + ((id >> 3) & 3);
    const int t0 = (31 - (id >> 5)) * 64;       // descending work (LPT)
    const u16* Qh = Qw + (size_t)bh * S * DK;
    const u16* Kh = Kw + (size_t)bh * S * DK;
    u16* Vh = Vtw + (size_t)bh * DK * S;

    __shared__ u16 Qs[2][64][64];
    __shared__ float zbuf[64];

    const int tid = threadIdx.x;
    const int w = tid >> 6, ln = tid & 15, hi = (tid & 63) >> 4;
    const int e0 = tid >> 3, sc = tid & 7;

    char* qb0 = (char*)&Qs[0][0][0];
    char* qb1 = (char*)&Qs[1][0][0];
    auto swz = [](int row, int colb) { return (row * 128 + colb) ^ ((row & 7) << 4); };

    short8 ak[2];
    #pragma unroll
    for (int ks = 0; ks < 2; ++ks)
        ak[ks] = *reinterpret_cast<const short8*>(
            &Kh[(size_t)(t0 + w * 16 + ln) * DK + ks * 32 + hi * 8]);

    float zs[4] = {0.f, 0.f, 0.f, 0.f};

    {
        short8 a = *reinterpret_cast<const short8*>(&Qh[(size_t)e0 * DK + sc * 8]);
        short8 b = *reinterpret_cast<const short8*>(&Qh[(size_t)(e0 + 32) * DK + sc * 8]);
        *reinterpret_cast<short8*>(qb0 + swz(e0, sc * 16)) = a;
        *reinterpret_cast<short8*>(qb0 + swz(e0 + 32, sc * 16)) = b;
    }
    __syncthreads();

    int cur = 0;
    for (int s0b = 0; s0b <= t0; s0b += 64) {
        const bool nxt = (s0b + 64 <= t0);
        short8 nq0, nq1;
        if (nxt) {
            nq0 = *reinterpret_cast<const short8*>(&Qh[(size_t)(s0b + 64 + e0) * DK + sc * 8]);
            nq1 = *reinterpret_cast<const short8*>(&Qh[(size_t)(s0b + 96 + e0) * DK + sc * 8]);
        }
        char* qb = cur ? qb1 : qb0;
        f32x4 c[4];
        #pragma unroll
        for (int n = 0; n < 4; ++n) c[n] = f32x4{0.f, 0.f, 0.f, 0.f};
        #pragma unroll
        for (int ks = 0; ks < 2; ++ks)
            #pragma unroll
            for (int n = 0; n < 4; ++n) {
                short8 bqf = *reinterpret_cast<const short8*>(
                    qb + swz(n * 16 + ln, ks * 64 + hi * 16));
                c[n] = MFMA16(ak[ks], bqf, c[n]);
            }
        if (s0b == t0) {
            #pragma unroll
            for (int n = 0; n < 4; ++n)
                #pragma unroll
                for (int r = 0; r < 4; ++r)
                    if (s0b + n * 16 + ln > t0 + w * 16 + hi * 4 + r)
                        c[n][r] = -INFINITY;
        }
        #pragma unroll
        for (int n = 0; n < 4; ++n)
            #pragma unroll
            for (int r = 0; r < 4; ++r)
                zs[r] += __expf(c[n][r]);
        if (nxt) {
            char* qn = cur ? qb0 : qb1;
            *reinterpret_cast<short8*>(qn + swz(e0, sc * 16)) = nq0;
            *reinterpret_cast<short8*>(qn + swz(e0 + 32, sc * 16)) = nq1;
        }
        __syncthreads();
        cur ^= 1;
    }

    #pragma unroll
    for (int r = 0; r < 4; ++r) {
        #pragma unroll
        for (int msk = 1; msk < 16; msk <<= 1)
            zs[r] += __shfl_xor(zs[r], msk, 64);
    }
    if (ln == 0) {
        #pragma unroll
        for (int r = 0; r < 4; ++r)
            zbuf[w * 16 + hi * 4 + r] = 1.f / zs[r];
    }
    __syncthreads();

    float iz[8];
    #pragma unroll
    for (int j = 0; j < 8; ++j) iz[j] = zbuf[sc * 8 + j];
    #pragma unroll
    for (int pass = 0; pass < 2; ++pass) {
        int e = e0 + 32 * pass;
        u16* vp = &Vh[(size_t)e * S + t0 + sc * 8];
        short8 v = *reinterpret_cast<short8*>(vp);
        short8 o;
        #pragma unroll
        for (int j = 0; j < 8; ++j) o[j] = (short)f2b(b2f(v[j]) * iz[j]);
        *reinterpret_cast<short8*>(vp) = o;
    }
}

// ---------------------------------------------------------------------------
// P.V with V pre-scaled by 1/Z (P = raw exp).  Round-9 form: grid 1024,
// XCD-swizzled; V reg-staged into LDS dbuf; K reg ping-pong; 2 barriers/tile.
// Output bf16 (only epilogue differs from round 9).
// ---------------------------------------------------------------------------
__global__ __launch_bounds__(256) void attn_pv(
    const u16* __restrict__ Qw, const u16* __restrict__ Kw, const u16* __restrict__ Vtw,
    u16* __restrict__ combined)
{
    const int id = blockIdx.x;
    const int bh = (id & 7) * 4 + ((id >> 3) & 3);
    const int s0 = (id >> 5) * 64;              // s0=0 (most work) first
    const int bidx = bh >> 4, h = bh & 15;
    const u16* Qh = Qw + (size_t)bh * S * DK;
    const u16* Kh = Kw + (size_t)bh * S * DK;
    const u16* Vh = Vtw + (size_t)bh * DK * S;

    __shared__ u16 Vs[2][64][64];
    __shared__ u16 Ps[64][72];

    const int tid = threadIdx.x;
    const int w = tid >> 6, ln = tid & 15, hi = (tid & 63) >> 4;
    const int e0 = tid >> 3, sc = tid & 7;

    char* vb0 = (char*)&Vs[0][0][0];
    char* vb1 = (char*)&Vs[1][0][0];
    auto swz = [](int row, int colb) { return (row * 128 + colb) ^ ((row & 7) << 4); };

    short8 bq[4][2];
    #pragma unroll
    for (int n = 0; n < 4; ++n)
        #pragma unroll
        for (int ks = 0; ks < 2; ++ks)
            bq[n][ks] = *reinterpret_cast<const short8*>(
                &Qh[(size_t)(s0 + n * 16 + ln) * DK + ks * 32 + hi * 8]);

    f32x4 acc[4];
    #pragma unroll
    for (int n = 0; n < 4; ++n) acc[n] = f32x4{0.f, 0.f, 0.f, 0.f};

    {
        short8 a = *reinterpret_cast<const short8*>(&Vh[(size_t)e0 * S + s0 + sc * 8]);
        short8 b = *reinterpret_cast<const short8*>(&Vh[(size_t)(e0 + 32) * S + s0 + sc * 8]);
        *reinterpret_cast<short8*>(vb0 + swz(e0, sc * 16)) = a;
        *reinterpret_cast<short8*>(vb0 + swz(e0 + 32, sc * 16)) = b;
    }

    short8 akA[2], akB[2];
    auto loadK = [&](short8 (&ak)[2], int t1) {
        #pragma unroll
        for (int ks = 0; ks < 2; ++ks)
            ak[ks] = *reinterpret_cast<const short8*>(
                &Kh[(size_t)(t1 + w * 16 + ln) * DK + ks * 32 + hi * 8]);
    };

    loadK(akA, s0);
    __syncthreads();
    int cur = 0;

    auto tile = [&](short8 (&ak)[2], int t1) {
        const bool nxt = (t1 + 64 < S);
        short8 nv0, nv1;
        if (nxt) {
            nv0 = *reinterpret_cast<const short8*>(&Vh[(size_t)e0 * S + t1 + 64 + sc * 8]);
            nv1 = *reinterpret_cast<const short8*>(&Vh[(size_t)(e0 + 32) * S + t1 + 64 + sc * 8]);
        }

        f32x4 st[4];
        #pragma unroll
        for (int n = 0; n < 4; ++n) st[n] = f32x4{0.f, 0.f, 0.f, 0.f};
        #pragma unroll
        for (int ks = 0; ks < 2; ++ks)
            #pragma unroll
            for (int n = 0; n < 4; ++n)
                st[n] = MFMA16(ak[ks], bq[n][ks], st[n]);

        const bool diag = (t1 == s0);
        #pragma unroll
        for (int n = 0; n < 4; ++n) {
            short4v pk;
            #pragma unroll
            for (int r = 0; r < 4; ++r) {
                float p = __expf(st[n][r]);
                if (diag && (s0 + n * 16 + ln) > (t1 + w * 16 + hi * 4 + r)) p = 0.f;
                pk[r] = (short)f2b(p);
            }
            *reinterpret_cast<short4v*>(&Ps[n * 16 + ln][w * 16 + hi * 4]) = pk;
        }
        __syncthreads();   // P visible to all waves

        char* vb = cur ? vb1 : vb0;
        short8 pa[2];
        #pragma unroll
        for (int ks = 0; ks < 2; ++ks)
            pa[ks] = *reinterpret_cast<const short8*>(&Ps[w * 16 + ln][ks * 32 + hi * 8]);
        #pragma unroll
        for (int ks = 0; ks < 2; ++ks)
            #pragma unroll
            for (int n = 0; n < 4; ++n) {
                short8 vv = *reinterpret_cast<const short8*>(
                    vb + swz(n * 16 + ln, ks * 64 + hi * 16));
                acc[n] = MFMA16(pa[ks], vv, acc[n]);
            }

        if (nxt) {
            char* vn = cur ? vb0 : vb1;
            *reinterpret_cast<short8*>(vn + swz(e0, sc * 16)) = nv0;
            *reinterpret_cast<short8*>(vn + swz(e0 + 32, sc * 16)) = nv1;
        }
        __syncthreads();   // P consumed; next V staged
        cur ^= 1;
    };

    int t1 = s0;
    while (t1 < S) {
        if (t1 + 64 < S) loadK(akB, t1 + 64);
        tile(akA, t1);
        t1 += 64;
        if (t1 >= S) break;
        if (t1 + 64 < S) loadK(akA, t1 + 64);
        tile(akB, t1);
        t1 += 64;
    }

    #pragma unroll
    for (int n = 0; n < 4; ++n)
        #pragma unroll
        for (int r = 0; r < 4; ++r) {
            int s = s0 + w * 16 + hi * 4 + r;
            combined[((size_t)bidx * S + s) * D + h * DK + n * 16 + ln] = f2b(acc[n][r]);
        }
}

// ---------------------------------------------------------------------------
// x1b = bf16(layernorm(a + bsrc(bf16))) — fp32 output elided.
// ---------------------------------------------------------------------------
__global__ __launch_bounds__(256) void add_ln_b(
    const float* __restrict__ a, const u16* __restrict__ bsrc,
    u16* __restrict__ outb)
{
    const int row = blockIdx.x;
    const int tid = threadIdx.x;
    const size_t base = (size_t)row * D;

    float v[4];
    float sum = 0.f;
    #pragma unroll
    for (int i = 0; i < 4; ++i) {
        int c = tid + i * 256;
        float t = a[base + c] + b2f(bsrc[base + c]);
        v[i] = t;
        sum += t;
    }

    __shared__ float red[8];
    #pragma unroll
    for (int o = 32; o > 0; o >>= 1) sum += __shfl_down(sum, o, 64);
    const int lane = tid & 63, w = tid >> 6;
    if (lane == 0) red[w] = sum;
    __syncthreads();
    const float mean = (red[0] + red[1] + red[2] + red[3]) * (1.f / D);

    float s2 = 0.f;
    #pragma unroll
    for (int i = 0; i < 4; ++i) { float d2 = v[i] - mean; s2 += d2 * d2; }
    #pragma unroll
    for (int o = 32; o > 0; o >>= 1) s2 += __shfl_down(s2, o, 64);
    if (lane == 0) red[4 + w] = s2;
    __syncthreads();
    const float var = (red[4] + red[5] + red[6] + red[7]) * (1.f / (D - 1));
    const float scale = 1.f / (sqrtf(var) + 1e-4f);

    #pragma unroll
    for (int i = 0; i < 4; ++i) {
        int c = tid + i * 256;
        outb[base + c] = f2b((v[i] - mean) * scale);
    }
}

// ---------------------------------------------------------------------------
// out = layernorm(a) with bf16 input — final LN.
// ---------------------------------------------------------------------------
__global__ __launch_bounds__(256) void ln_final(
    const u16* __restrict__ a, float* __restrict__ out)
{
    const int row = blockIdx.x;
    const int tid = threadIdx.x;
    const size_t base = (size_t)row * D;

    float v[4];
    float sum = 0.f;
    #pragma unroll
    for (int i = 0; i < 4; ++i) {
        int c = tid + i * 256;
        v[i] = b2f(a[base + c]);
        sum += v[i];
    }

    __shared__ float red[8];
    #pragma unroll
    for (int o = 32; o > 0; o >>= 1) sum += __shfl_down(sum, o, 64);
    const int lane = tid & 63, w = tid >> 6;
    if (lane == 0) red[w] = sum;
    __syncthreads();
    const float mean = (red[0] + red[1] + red[2] + red[3]) * (1.f / D);

    float s2 = 0.f;
    #pragma unroll
    for (int i = 0; i < 4; ++i) { float d2 = v[i] - mean; s2 += d2 * d2; }
    #pragma unroll
    for (int o = 32; o > 0; o >>= 1) s2 += __shfl_down(s2, o, 64);
    if (lane == 0) red[4 + w] = s2;
    __syncthreads();
    const float var = (red[4] + red[5] + red[6] + red[7]) * (1.f / (D - 1));
    const float scale = 1.f / (sqrtf(var) + 1e-4f);

    #pragma unroll
    for (int i = 0; i < 4; ++i) {
        int c = tid + i * 256;
        out[base + c] = (v[i] - mean) * scale;
    }
}

// ---------------------------------------------------------------------------
// FFN: x2b = bf16(x1 + x1b @ WffT^T + bff), residual read from bf16 x1b.
// 1D grid 256, XCD-swizzled.  global_load_lds + pre-swizzled-source + dbuf.
// ---------------------------------------------------------------------------
__global__ __launch_bounds__(256) void ffn(
    const u16* __restrict__ x1b, const u16* __restrict__ WffT,
    const float* __restrict__ bff, u16* __restrict__ x2b)
{
    const int id = blockIdx.x;
    const int m0 = ((id & 7) * 4 + ((id >> 3) & 3)) * 128;
    const int n0 = (id >> 5) * 128;

    __shared__ u16 SM[2][2][128][64];       // [buf][A/B][row][col], 64KB

    const int tid = threadIdx.x;
    const int w = tid >> 6, ln = tid & 15, hi = (tid & 63) >> 4;
    const int wm = w >> 1, wn = w & 1;
    const int l  = tid & 63;
    const int lr = l >> 3;
    const int lc8 = ((l & 7) ^ lr) * 8;

    char* sA0 = (char*)&SM[0][0][0][0];
    char* sB0 = (char*)&SM[0][1][0][0];
    char* sA1 = (char*)&SM[1][0][0][0];
    char* sB1 = (char*)&SM[1][1][0][0];
    auto swz = [](int r, int cb) { return r * 128 + (cb ^ ((r & 7) << 4)); };

    f32x4 acc[4][4];
    #pragma unroll
    for (int m = 0; m < 4; ++m)
        #pragma unroll
        for (int n = 0; n < 4; ++n) acc[m][n] = f32x4{0.f, 0.f, 0.f, 0.f};

    auto stage = [&](char* sa, char* sb, int k0) {
        #pragma unroll
        for (int c = 0; c < 4; ++c) {
            int rbase = w * 32 + c * 8;
            int row = rbase + lr;
            gload16(&x1b[(size_t)(m0 + row) * D + k0 + lc8], (u16*)(sa + rbase * 128));
            gload16(&WffT[(size_t)(n0 + row) * D + k0 + lc8], (u16*)(sb + rbase * 128));
        }
    };

    stage(sA0, sB0, 0);
    __syncthreads();

    for (int it = 0; it < 16; ++it) {
        char* ac = (it & 1) ? sA1 : sA0;
        char* bc = (it & 1) ? sB1 : sB0;
        if (it + 1 < 16)
            stage((it & 1) ? sA0 : sA1, (it & 1) ? sB0 : sB1, (it + 1) * 64);
        #pragma unroll
        for (int ks = 0; ks < 2; ++ks) {
            short8 af[4], bf[4];
            #pragma unroll
            for (int m = 0; m < 4; ++m)
                af[m] = *reinterpret_cast<const short8*>(
                    ac + swz(wm * 64 + m * 16 + ln, ks * 64 + hi * 16));
            #pragma unroll
            for (int n = 0; n < 4; ++n)
                bf[n] = *reinterpret_cast<const short8*>(
                    bc + swz(wn * 64 + n * 16 + ln, ks * 64 + hi * 16));
            #pragma unroll
            for (int m = 0; m < 4; ++m)
                #pragma unroll
                for (int n = 0; n < 4; ++n)
                    acc[m][n] = MFMA16(af[m], bf[n], acc[m][n]);
        }
        __syncthreads();
    }

    float bf4[4];
    #pragma unroll
    for (int n = 0; n < 4; ++n) bf4[n] = bff[n0 + wn * 64 + n * 16 + ln];

    #pragma unroll
    for (int m = 0; m < 4; ++m)
        #pragma unroll
        for (int n = 0; n < 4; ++n)
            #pragma unroll
            for (int r = 0; r < 4; ++r) {
                int row = m0 + wm * 64 + m * 16 + hi * 4 + r;
                int col = n0 + wn * 64 + n * 16 + ln;
                size_t idx = (size_t)row * D + col;
                float xres = b2f(x1b[idx]);
                x2b[idx] = f2b(xres + acc[m][n][r] + bf4[n]);
            }
}

// ---------------------------------------------------------------------------
extern "C" void kernel_launch(void* const* d_in, const int* in_sizes, int n_in,
                              void* d_out, int out_size, void* d_ws, size_t ws_size,
                              hipStream_t stream)
{
    const float* x   = (const float*)d_in[0];
    const float* Wq  = (const float*)d_in[1];
    const float* bq  = (const float*)d_in[2];
    const float* Wk  = (const float*)d_in[3];
    const float* bk  = (const float*)d_in[4];
    const float* Wv  = (const float*)d_in[5];
    const float* bv  = (const float*)d_in[6];
    const float* Wff = (const float*)d_in[7];
    const float* bff = (const float*)d_in[8];
    float* out = (float*)d_out;

    const size_t NX = (size_t)BS * D;          // 4,194,304
    char* p = (char*)d_ws;
    auto alloc = [&](size_t bytes) { char* r = p; p += bytes; return r; };

    u16* xb    = (u16*)alloc(NX * 2);
    u16* WT    = (u16*)alloc((size_t)3 * H * DK * D * 2);   // [3072][1024]
    u16* WffT  = (u16*)alloc((size_t)D * D * 2);
    u16* Qw    = (u16*)alloc(NX * 2);
    u16* Kw    = (u16*)alloc(NX * 2);
    u16* Vtw   = (u16*)alloc(NX * 2);
    u16* combined = (u16*)alloc(NX * 2);
    u16*   x1b = xb;          // xb dead after qkv_gemm
    u16*   x2b = Qw;          // Qw dead after attn_pv

    convert_x<<<dim3(NX / 2048), 256, 0, stream>>>(x, xb);
    tconv3<<<dim3(1, 16, 48), 256, 0, stream>>>(Wq, Wk, Wv, WT);
    tconv<<<dim3(16, 16, 1), 256, 0, stream>>>(Wff, WffT, D, D);

    qkv_gemm<<<dim3(768), 256, 0, stream>>>(
        xb, WT, bq, bk, bv, Qw, Kw, Vtw);

    col_stats<<<dim3(1024), 256, 0, stream>>>(Qw, Kw, Vtw);

    attn_pv<<<dim3(1024), 256, 0, stream>>>(Qw, Kw, Vtw, combined);

    add_ln_b<<<BS, 256, 0, stream>>>(x, combined, x1b);

    ffn<<<dim3(256), 256, 0, stream>>>(x1b, WffT, bff, x2b);

    ln_final<<<BS, 256, 0, stream>>>(x2b, out);
}